// Round 8
// baseline (8396.883 us; speedup 1.0000x reference)
//
#include <hip/hip_runtime.h>
#include <math.h>

#define BB 32
#define TT 512
#define FF 1024
#define UU 1024
#define NWRK 8            // worker blocks per XCD
#define GRID 1024         // oversubscribed launch; extras exit after registration

typedef __attribute__((ext_vector_type(8))) short s8v;    // 8 x bf16 (4 VGPR)
typedef __attribute__((ext_vector_type(4))) float f4v;    // 4 x f32
typedef __attribute__((ext_vector_type(2))) float f2v;    // 2 x f32

static __device__ __forceinline__ unsigned short f2bf(float f) {
    unsigned int u = __builtin_bit_cast(unsigned int, f);
    u += 0x7fff + ((u >> 16) & 1);          // RNE
    return (unsigned short)(u >> 16);
}
static __device__ __forceinline__ float bf2f(unsigned short b) {
    unsigned int u = ((unsigned int)b) << 16;
    return __builtin_bit_cast(float, u);
}

// ---- device-coherent accesses (bypass non-coherent L1/L2; no fences needed) ----
static __device__ __forceinline__ s8v ld_b128_sc(const void* p) {
    s8v r;
    asm volatile("global_load_dwordx4 %0, %1, off sc0 sc1" : "=v"(r) : "v"(p));
    return r;
}
static __device__ __forceinline__ f4v ld_f128_sc(const void* p) {
    f4v r;
    asm volatile("global_load_dwordx4 %0, %1, off sc0 sc1" : "=v"(r) : "v"(p));
    return r;
}
static __device__ __forceinline__ f2v ld_f64_sc(const void* p) {
    f2v r;
    asm volatile("global_load_dwordx2 %0, %1, off sc0 sc1" : "=v"(r) : "v"(p));
    return r;
}
static __device__ __forceinline__ void st_b128_sc(void* p, f4v v) {
    asm volatile("global_store_dwordx4 %0, %1, off sc0 sc1" :: "v"(p), "v"(v));
}
static __device__ __forceinline__ void st_b64u_sc(void* p, uint2 v) {
    asm volatile("global_store_dwordx2 %0, %1, off sc0 sc1" :: "v"(p), "v"(v));
}
static __device__ __forceinline__ void st_f64_sc(void* p, f2v v) {
    asm volatile("global_store_dwordx2 %0, %1, off sc0 sc1" :: "v"(p), "v"(v));
}
static __device__ __forceinline__ void st_b32_sc(void* p, unsigned int v) {
    asm volatile("global_store_dword %0, %1, off sc0 sc1" :: "v"(p), "v"(v));
}
static __device__ __forceinline__ void vm_drain_schedfence() {
    asm volatile("s_waitcnt vmcnt(0)" ::: "memory");
    __builtin_amdgcn_sched_barrier(0);
}

// ---------------------------------------------------------------------------
__global__ __launch_bounds__(256) void cvt_bf16(
    const float* __restrict__ in, unsigned short* __restrict__ out, int n4)
{
    int i = blockIdx.x * 256 + threadIdx.x;
    if (i < n4) {
        float4 v = ((const float4*)in)[i];
        ushort4 o;
        o.x = f2bf(v.x); o.y = f2bf(v.y); o.z = f2bf(v.z); o.w = f2bf(v.w);
        ((ushort4*)out)[i] = o;
    }
}

// ---------------------------------------------------------------------------
template<int ROWS, int COLS>
__global__ __launch_bounds__(256) void transpose_bf16(
    const float* __restrict__ W, unsigned short* __restrict__ WT)
{
    __shared__ float tl[32][33];
    const int tx = threadIdx.x, ty = threadIdx.y;   // block (32, 8)
    const int bx = blockIdx.x, by = blockIdx.y;
    #pragma unroll
    for (int i = 0; i < 4; ++i) {
        int r = by * 32 + ty + i * 8;
        int c = bx * 32 + tx;
        tl[ty + i * 8][tx] = W[(size_t)r * COLS + c];
    }
    __syncthreads();
    #pragma unroll
    for (int i = 0; i < 4; ++i) {
        int n = bx * 32 + ty + i * 8;
        int k = by * 32 + tx;
        WT[(size_t)n * ROWS + k] = f2bf(tl[tx][ty + i * 8]);
    }
}

// ---------------------------------------------------------------------------
__global__ __launch_bounds__(256) void gemm_xproj(
    const unsigned short* __restrict__ A,    // [M][1024]
    const unsigned short* __restrict__ BT,   // [N][2048]
    unsigned short* __restrict__ C,          // [M][N]
    int N)
{
    __shared__ unsigned short Al[128][72];
    __shared__ unsigned short Bl[128][72];
    const int tid  = threadIdx.x;
    const int lane = tid & 63;
    const int wave = tid >> 6;
    const int l15  = lane & 15;
    const int kg   = lane >> 4;
    const int m0   = blockIdx.y * 128;
    const int n0   = blockIdx.x * 128;
    const int rowOff = (wave >> 1) * 64;
    const int colOff = (wave & 1) * 64;

    f4v acc[4][4];
    #pragma unroll
    for (int m = 0; m < 4; ++m)
        #pragma unroll
        for (int n = 0; n < 4; ++n) acc[m][n] = (f4v){0.f, 0.f, 0.f, 0.f};

    for (int k0 = 0; k0 < 1024; k0 += 64) {
        #pragma unroll
        for (int it = 0; it < 4; ++it) {
            int c = tid + it * 256;
            int r = c >> 3, off = (c & 7) * 8;
            *(s8v*)&Al[r][off] = *(const s8v*)(A + (size_t)(m0 + r) * 1024 + k0 + off);
            *(s8v*)&Bl[r][off] = *(const s8v*)(BT + (size_t)(n0 + r) * 2048 + k0 + off);
        }
        __syncthreads();
        #pragma unroll
        for (int ks = 0; ks < 2; ++ks) {
            s8v a[4], b[4];
            #pragma unroll
            for (int m = 0; m < 4; ++m)
                a[m] = *(const s8v*)&Al[rowOff + m * 16 + l15][ks * 32 + kg * 8];
            #pragma unroll
            for (int n = 0; n < 4; ++n)
                b[n] = *(const s8v*)&Bl[colOff + n * 16 + l15][ks * 32 + kg * 8];
            #pragma unroll
            for (int m = 0; m < 4; ++m)
                #pragma unroll
                for (int n = 0; n < 4; ++n)
                    acc[m][n] = __builtin_amdgcn_mfma_f32_16x16x32_bf16(a[m], b[n], acc[m][n], 0, 0, 0);
        }
        __syncthreads();
    }
    #pragma unroll
    for (int m = 0; m < 4; ++m)
        #pragma unroll
        for (int n = 0; n < 4; ++n)
            #pragma unroll
            for (int i = 0; i < 4; ++i) {
                int row = m0 + rowOff + m * 16 + kg * 4 + i;
                int col = n0 + colOff + n * 16 + l15;
                C[(size_t)row * N + col] = f2bf(acc[m][n][i]);
            }
}

// ---------------------------------------------------------------------------
// XCD-pair persistent GRU.
// 1024 blocks launched; each reads its physical XCC_ID, takes a rank within
// its XCD (agent atomic); ranks >= 8 exit. Pair p = {XCD 2p, 2p+1} owns
// batches [8p, 8p+8) and runs an independent 512-step recurrence with
// 16-wide pair-local barriers.
//   even XCD ("R"): gate cols [0,1024)    + cand cols [0,512)
//   odd  XCD ("U"): gate cols [1024,2048) + cand cols [512,1024)
//   worker rank k: gate cols [side*1024 + k*128, +128),
//                  cand cols [side*512  + k*64,  +64)
// Per-XCD weight slice = 3 MB -> L2-resident (no fences ever invalidate).
// State (h/hb/rhb/ub) via sc0sc1; h at own cand cols persisted in registers.
// ---------------------------------------------------------------------------
__global__ __launch_bounds__(256, 1) void gru_pair(
    const unsigned short* __restrict__ WgT,   // [2048][2048] bf16
    const unsigned short* __restrict__ WcT,   // [1024][2048] bf16
    const unsigned short* __restrict__ Xgb,   // [B*T][2048] bf16
    const unsigned short* __restrict__ Xcb,   // [B*T][1024] bf16
    const float* __restrict__ bg,             // [2048]
    const float* __restrict__ bc,             // [1024]
    float* __restrict__ h,                    // [32][1024] f32
    unsigned short* __restrict__ hb,          // [32][1024] bf16
    unsigned short* __restrict__ rhb,         // [32][1024] bf16
    float* __restrict__ ub,                   // [32][1024] f32
    float* __restrict__ out,                  // [B][T][U] f32
    unsigned* __restrict__ bar)               // pair counters + registration
{
    __shared__ float red[4][8][8][16];        // 16 KB [wave][ntile][row][col]
    __shared__ int rank_sh;
    const int tid  = threadIdx.x;
    const int lane = tid & 63;
    const int wave = tid >> 6;
    const int l15  = lane & 15;
    const int kg   = lane >> 4;

    // ---- registration: physical XCD id + rank within XCD ----
    int xcd;
    asm volatile("s_getreg_b32 %0, hwreg(HW_REG_XCC_ID)" : "=s"(xcd));
    xcd &= 7;
    if (tid == 0)
        rank_sh = (int)__hip_atomic_fetch_add(bar + 512 + xcd, 1u,
                                              __ATOMIC_RELAXED, __HIP_MEMORY_SCOPE_AGENT);
    __syncthreads();
    const int rank = rank_sh;
    if (rank >= NWRK) return;                 // extras exit immediately

    const int p    = xcd >> 1;
    const int side = xcd & 1;
    const int b0   = p * 8;                   // 8 batches per pair
    unsigned* cnt  = bar + p * 64;            // pair-private counter line

    const int gj0 = side * 1024 + rank * 128; // 128 gate cols
    const int cj0 = side * 512  + rank * 64;  // 64 cand cols
    const int kofs = wave * 256;              // per-wave K slice
    const int arow = b0 + (l15 & 7);          // 8 batches duplicated into 16 rows

    // epilogue mappings
    const int er  = tid >> 5;                 // 0..7 (batch row)
    const int ec4 = (tid & 31) * 4;           // gate col offset 0..124
    const int ec2 = (tid & 31) * 2;           // cand col offset 0..62
    const int eb  = b0 + er;

    const f4v bg4 = *(const f4v*)(bg + gj0 + ec4);
    const float2 bc2 = *(const float2*)(bc + cj0 + ec2);

    auto pbar = [&](unsigned tgt) {
        asm volatile("s_waitcnt vmcnt(0)" ::: "memory");
        __syncthreads();
        if (tid == 0) {
            __hip_atomic_fetch_add(cnt, 1u, __ATOMIC_RELAXED, __HIP_MEMORY_SCOPE_AGENT);
            while (__hip_atomic_load(cnt, __ATOMIC_RELAXED, __HIP_MEMORY_SCOPE_AGENT) < tgt)
                __builtin_amdgcn_s_sleep(1);
        }
        __syncthreads();
    };

    f2v hv = (f2v){0.f, 0.f};                 // own h cols (register-resident)
    ushort4 xg = *(const ushort4*)(Xgb + ((size_t)eb * TT + 0) * 2048 + gj0 + ec4);

    for (int t = 0; t < TT; ++t) {
        // ================= phase G: gates (128 cols) =================
        ushort2 xc = *(const ushort2*)(Xcb + ((size_t)eb * TT + t) * 1024 + cj0 + ec2);
        f4v hsl = (f4v){0.f, 0.f, 0.f, 0.f};
        if (side == 0) hsl = ld_f128_sc(h + (size_t)eb * UU + gj0 + ec4);

        s8v a[8];
        #pragma unroll
        for (int kk = 0; kk < 8; ++kk)
            a[kk] = ld_b128_sc(hb + (size_t)arow * UU + kofs + kk * 32 + kg * 8);
        vm_drain_schedfence();

        f4v acc[8];
        #pragma unroll
        for (int n = 0; n < 8; ++n) acc[n] = (f4v){0.f, 0.f, 0.f, 0.f};
        #pragma unroll
        for (int n = 0; n < 8; ++n) {
            s8v bf[8];
            #pragma unroll
            for (int kk = 0; kk < 8; ++kk)
                bf[kk] = *(const s8v*)(WgT + (size_t)(gj0 + n * 16 + l15) * 2048
                                            + 1024 + kofs + kk * 32 + kg * 8);
            #pragma unroll
            for (int kk = 0; kk < 8; ++kk)
                acc[n] = __builtin_amdgcn_mfma_f32_16x16x32_bf16(a[kk], bf[kk], acc[n], 0, 0, 0);
        }
        if (kg < 2) {
            #pragma unroll
            for (int n = 0; n < 8; ++n)
                #pragma unroll
                for (int i = 0; i < 4; ++i)
                    red[wave][n][kg * 4 + i][l15] = acc[n][i];
        }
        __syncthreads();

        {
            const int nt = ec4 >> 4, cb = ec4 & 15;
            f4v pre = *(const f4v*)&red[0][nt][er][cb];
            #pragma unroll
            for (int w = 1; w < 4; ++w) pre += *(const f4v*)&red[w][nt][er][cb];
            pre[0] += bf2f(xg.x) + bg4[0];
            pre[1] += bf2f(xg.y) + bg4[1];
            pre[2] += bf2f(xg.z) + bg4[2];
            pre[3] += bf2f(xg.w) + bg4[3];
            float s0 = 1.f / (1.f + __expf(-pre[0]));
            float s1 = 1.f / (1.f + __expf(-pre[1]));
            float s2 = 1.f / (1.f + __expf(-pre[2]));
            float s3 = 1.f / (1.f + __expf(-pre[3]));
            if (side == 0) {                  // r gates -> rh (bf16)
                uint2 pk;
                pk.x = (unsigned int)f2bf(s0 * hsl[0]) | ((unsigned int)f2bf(s1 * hsl[1]) << 16);
                pk.y = (unsigned int)f2bf(s2 * hsl[2]) | ((unsigned int)f2bf(s3 * hsl[3]) << 16);
                st_b64u_sc(rhb + (size_t)eb * UU + gj0 + ec4, pk);
            } else {                          // u gates (fp32)
                st_b128_sc(ub + (size_t)eb * UU + (gj0 - 1024) + ec4, (f4v){s0, s1, s2, s3});
            }
        }
        pbar((unsigned)(2 * t + 1) * 16);

        // ================= phase C: candidate (64 cols) + update =================
        f2v uv = ld_f64_sc(ub + (size_t)eb * UU + cj0 + ec2);
        s8v ac[8];
        #pragma unroll
        for (int kk = 0; kk < 8; ++kk)
            ac[kk] = ld_b128_sc(rhb + (size_t)arow * UU + kofs + kk * 32 + kg * 8);
        // prefetch next step's Xg while waiting on memory anyway
        ushort4 xgn = xg;
        if (t + 1 < TT)
            xgn = *(const ushort4*)(Xgb + ((size_t)eb * TT + t + 1) * 2048 + gj0 + ec4);
        vm_drain_schedfence();

        f4v acc2[4];
        #pragma unroll
        for (int n = 0; n < 4; ++n) acc2[n] = (f4v){0.f, 0.f, 0.f, 0.f};
        #pragma unroll
        for (int n = 0; n < 4; ++n) {
            s8v bf[8];
            #pragma unroll
            for (int kk = 0; kk < 8; ++kk)
                bf[kk] = *(const s8v*)(WcT + (size_t)(cj0 + n * 16 + l15) * 2048
                                            + 1024 + kofs + kk * 32 + kg * 8);
            #pragma unroll
            for (int kk = 0; kk < 8; ++kk)
                acc2[n] = __builtin_amdgcn_mfma_f32_16x16x32_bf16(ac[kk], bf[kk], acc2[n], 0, 0, 0);
        }
        if (kg < 2) {
            #pragma unroll
            for (int n = 0; n < 4; ++n)
                #pragma unroll
                for (int i = 0; i < 4; ++i)
                    red[wave][n][kg * 4 + i][l15] = acc2[n][i];
        }
        __syncthreads();

        {
            const int nt = ec2 >> 4, cb = ec2 & 15;
            float2 pre2 = *(const float2*)&red[0][nt][er][cb];
            #pragma unroll
            for (int w = 1; w < 4; ++w) {
                float2 q = *(const float2*)&red[w][nt][er][cb];
                pre2.x += q.x; pre2.y += q.y;
            }
            float c0 = pre2.x + bf2f(xc.x) + bc2.x;
            float c1 = pre2.y + bf2f(xc.y) + bc2.y;
            c0 = fminf(fmaxf(c0, -15.f), 15.f);
            c1 = fminf(fmaxf(c1, -15.f), 15.f);
            float e0 = __expf(2.f * c0), e1 = __expf(2.f * c1);
            float t0 = (e0 - 1.f) / (e0 + 1.f);
            float t1 = (e1 - 1.f) / (e1 + 1.f);
            float hn0 = uv[0] * hv[0] + (1.f - uv[0]) * t0;
            float hn1 = uv[1] * hv[1] + (1.f - uv[1]) * t1;
            hv = (f2v){hn0, hn1};             // persist own h in registers

            st_f64_sc(h + (size_t)eb * UU + cj0 + ec2, hv);
            st_b32_sc(hb + (size_t)eb * UU + cj0 + ec2,
                      (unsigned int)f2bf(hn0) | ((unsigned int)f2bf(hn1) << 16));
            *(float2*)(out + ((size_t)eb * TT + t) * UU + cj0 + ec2) = make_float2(hn0, hn1);
        }
        xg = xgn;
        pbar((unsigned)(2 * t + 2) * 16);
    }
}

// ===========================================================================
// Fallback per-step kernels (round-2, verified) — used only if ws too small.
// ===========================================================================
__global__ __launch_bounds__(256) void gru_gates2(
    const unsigned short* __restrict__ hb, const unsigned short* __restrict__ WgT,
    const unsigned short* __restrict__ Xgb, const float* __restrict__ bg,
    const float* __restrict__ h, unsigned short* __restrict__ rhb,
    float* __restrict__ ubuf, int t)
{
    __shared__ unsigned short hb_l[32][1032];
    __shared__ unsigned short Wl[16][1032];
    __shared__ float red[4][32][16];
    const int tid = threadIdx.x, lane = tid & 63, wave = tid >> 6;
    const int l15 = lane & 15, kg = lane >> 4;
    const int j0 = blockIdx.x * 16;
    #pragma unroll
    for (int it = 0; it < 16; ++it) {
        int c = tid + it * 256; int r = c >> 7, off = (c & 127) * 8;
        *(s8v*)&hb_l[r][off] = *(const s8v*)(hb + (size_t)r * 1024 + off);
    }
    #pragma unroll
    for (int it = 0; it < 8; ++it) {
        int c = tid + it * 256; int r = c >> 7, off = (c & 127) * 8;
        *(s8v*)&Wl[r][off] = *(const s8v*)(WgT + (size_t)(j0 + r) * 2048 + 1024 + off);
    }
    __syncthreads();
    f4v acc0 = (f4v){0.f,0.f,0.f,0.f}, acc1 = (f4v){0.f,0.f,0.f,0.f};
    const int kbase = wave * 256;
    #pragma unroll
    for (int kk = 0; kk < 8; ++kk) {
        int k = kbase + kk * 32 + kg * 8;
        s8v a0 = *(const s8v*)&hb_l[l15][k];
        s8v a1 = *(const s8v*)&hb_l[16 + l15][k];
        s8v b  = *(const s8v*)&Wl[l15][k];
        acc0 = __builtin_amdgcn_mfma_f32_16x16x32_bf16(a0, b, acc0, 0, 0, 0);
        acc1 = __builtin_amdgcn_mfma_f32_16x16x32_bf16(a1, b, acc1, 0, 0, 0);
    }
    #pragma unroll
    for (int i = 0; i < 4; ++i) {
        red[wave][kg * 4 + i][l15] = acc0[i];
        red[wave][16 + kg * 4 + i][l15] = acc1[i];
    }
    __syncthreads();
    for (int e = tid; e < 512; e += 256) {
        int b = e >> 4, col = e & 15;
        int j = j0 + col;
        float pre = red[0][b][col] + red[1][b][col] + red[2][b][col] + red[3][b][col];
        pre += bf2f(Xgb[((size_t)b * TT + t) * 2048 + j]) + bg[j];
        float s = 1.f / (1.f + __expf(-pre));
        if (j < UU) rhb[b * UU + j] = f2bf(s * h[b * UU + j]);
        else        ubuf[b * UU + (j - UU)] = s;
    }
}

__global__ __launch_bounds__(256) void gru_cand2(
    const unsigned short* __restrict__ rhb, const unsigned short* __restrict__ WcT,
    const unsigned short* __restrict__ Xcb, const float* __restrict__ bc,
    const float* __restrict__ ubuf, float* __restrict__ h,
    unsigned short* __restrict__ hb, float* __restrict__ out, int t)
{
    __shared__ unsigned short rh_l[32][1032];
    __shared__ unsigned short Wl[16][1032];
    __shared__ float red[4][32][16];
    const int tid = threadIdx.x, lane = tid & 63, wave = tid >> 6;
    const int l15 = lane & 15, kg = lane >> 4;
    const int j0 = blockIdx.x * 16;
    #pragma unroll
    for (int it = 0; it < 16; ++it) {
        int c = tid + it * 256; int r = c >> 7, off = (c & 127) * 8;
        *(s8v*)&rh_l[r][off] = *(const s8v*)(rhb + (size_t)r * 1024 + off);
    }
    #pragma unroll
    for (int it = 0; it < 8; ++it) {
        int c = tid + it * 256; int r = c >> 7, off = (c & 127) * 8;
        *(s8v*)&Wl[r][off] = *(const s8v*)(WcT + (size_t)(j0 + r) * 2048 + 1024 + off);
    }
    __syncthreads();
    f4v acc0 = (f4v){0.f,0.f,0.f,0.f}, acc1 = (f4v){0.f,0.f,0.f,0.f};
    const int kbase = wave * 256;
    #pragma unroll
    for (int kk = 0; kk < 8; ++kk) {
        int k = kbase + kk * 32 + kg * 8;
        s8v a0 = *(const s8v*)&rh_l[l15][k];
        s8v a1 = *(const s8v*)&rh_l[16 + l15][k];
        s8v b  = *(const s8v*)&Wl[l15][k];
        acc0 = __builtin_amdgcn_mfma_f32_16x16x32_bf16(a0, b, acc0, 0, 0, 0);
        acc1 = __builtin_amdgcn_mfma_f32_16x16x32_bf16(a1, b, acc1, 0, 0, 0);
    }
    #pragma unroll
    for (int i = 0; i < 4; ++i) {
        red[wave][kg * 4 + i][l15] = acc0[i];
        red[wave][16 + kg * 4 + i][l15] = acc1[i];
    }
    __syncthreads();
    for (int e = tid; e < 512; e += 256) {
        int b = e >> 4, col = e & 15;
        int j = j0 + col;
        float pre = red[0][b][col] + red[1][b][col] + red[2][b][col] + red[3][b][col];
        pre += bf2f(Xcb[((size_t)b * TT + t) * 1024 + j]) + bc[j];
        float cv = tanhf(pre);
        float u  = ubuf[b * UU + j];
        float hvv = h[b * UU + j];
        float hn = u * hvv + (1.f - u) * cv;
        h[b * UU + j]  = hn;
        hb[b * UU + j] = f2bf(hn);
        out[((size_t)b * TT + t) * UU + j] = hn;
    }
}

// ===========================================================================
extern "C" void kernel_launch(void* const* d_in, const int* in_sizes, int n_in,
                              void* d_out, int out_size, void* d_ws, size_t ws_size,
                              hipStream_t stream) {
    const float* x  = (const float*)d_in[0];
    const float* Wg = (const float*)d_in[1];
    const float* bg = (const float*)d_in[2];
    const float* Wc = (const float*)d_in[3];
    const float* bc = (const float*)d_in[4];
    float* out = (float*)d_out;

    const size_t XB_B  = (size_t)BB * TT * FF * 2;
    const size_t WGT_B = (size_t)2 * UU * (FF + UU) * 2;
    const size_t WCT_B = (size_t)UU * (FF + UU) * 2;
    const size_t XG_B  = (size_t)BB * TT * 2 * UU * 2;
    const size_t XC_B  = (size_t)BB * TT * UU * 2;
    const size_t H_B   = (size_t)BB * UU * 4;
    const size_t HB_B  = (size_t)BB * UU * 2;
    const size_t BAR_B = 4096;
    const size_t NEED  = XB_B + WGT_B + WCT_B + XG_B + XC_B + H_B + HB_B * 2 + H_B + BAR_B;

    char* p = (char*)d_ws;
    unsigned short* xb  = (unsigned short*)p;            p += XB_B;
    unsigned short* WgT = (unsigned short*)p;            p += WGT_B;
    unsigned short* WcT = (unsigned short*)p;            p += WCT_B;
    unsigned short* Xgb = (unsigned short*)p;            p += XG_B;
    unsigned short* Xcb = (unsigned short*)p;            p += XC_B;
    float*          h   = (float*)p;                     p += H_B;
    unsigned short* hb  = (unsigned short*)p;            p += HB_B;
    unsigned short* rhb = (unsigned short*)p;            p += HB_B;
    float*          ub  = (float*)p;                     p += H_B;
    unsigned*       bar = (unsigned*)p;                  p += BAR_B;

    // ---- one-time prep ----
    cvt_bf16<<<(BB * TT * FF / 4 + 255) / 256, 256, 0, stream>>>(x, xb, BB * TT * FF / 4);
    transpose_bf16<FF + UU, 2 * UU><<<dim3(64, 64), dim3(32, 8), 0, stream>>>(Wg, WgT);
    transpose_bf16<FF + UU, UU>    <<<dim3(32, 64), dim3(32, 8), 0, stream>>>(Wc, WcT);
    gemm_xproj<<<dim3(2 * UU / 128, BB * TT / 128), 256, 0, stream>>>(xb, WgT, Xgb, 2 * UU);
    gemm_xproj<<<dim3(UU / 128,     BB * TT / 128), 256, 0, stream>>>(xb, WcT, Xcb, UU);
    hipMemsetAsync(h,   0, H_B,   stream);
    hipMemsetAsync(hb,  0, HB_B,  stream);
    hipMemsetAsync(bar, 0, BAR_B, stream);

    if (ws_size >= NEED) {
        gru_pair<<<GRID, 256, 0, stream>>>(WgT, WcT, Xgb, Xcb, bg, bc,
                                           h, hb, rhb, ub, out, bar);
    } else {
        for (int t = 0; t < TT; ++t) {
            gru_gates2<<<128, 256, 0, stream>>>(hb, WgT, Xgb, bg, h, rhb, ub, t);
            gru_cand2 <<< 64, 256, 0, stream>>>(rhb, WcT, Xcb, bc, ub, h, hb, out, t);
        }
    }
}

// Round 10
// 6443.049 us; speedup vs baseline: 1.3032x; 1.3032x over previous
//
#include <hip/hip_runtime.h>
#include <math.h>

#define BB 32
#define TT 512
#define FF 1024
#define UU 1024
#define GRID 512          // oversubscribed; 8 workers/XCD self-select

typedef __attribute__((ext_vector_type(8))) short s8v;    // 8 x bf16 (4 VGPR)
typedef __attribute__((ext_vector_type(4))) float f4v;    // 4 x f32

static __device__ __forceinline__ unsigned short f2bf(float f) {
    unsigned int u = __builtin_bit_cast(unsigned int, f);
    u += 0x7fff + ((u >> 16) & 1);          // RNE
    return (unsigned short)(u >> 16);
}
static __device__ __forceinline__ float bf2f(unsigned short b) {
    unsigned int u = ((unsigned int)b) << 16;
    return __builtin_bit_cast(float, u);
}

// ---- PROVEN data path (R5/R7): device-coherent sc0 sc1, fence-free ----
static __device__ __forceinline__ s8v ld_b128_sc(const void* p) {
    s8v r;
    asm volatile("global_load_dwordx4 %0, %1, off sc0 sc1" : "=v"(r) : "v"(p));
    return r;
}
static __device__ __forceinline__ void st_b32_sc(void* p, unsigned int v) {
    asm volatile("global_store_dword %0, %1, off sc0 sc1" :: "v"(p), "v"(v));
}
// opaque plain load (un-rematerializable): pins weights in VGPRs
static __device__ __forceinline__ s8v ld_b128_pin(const void* p) {
    s8v r;
    asm volatile("global_load_dwordx4 %0, %1, off" : "=v"(r) : "v"(p));
    return r;
}
// XCD-local L2 atomics (signal fabric only — never data)
static __device__ __forceinline__ unsigned atom_add_ret_l2(unsigned* p, unsigned v) {
    unsigned old;
    asm volatile("global_atomic_add %0, %1, %2, off sc0\n\ts_waitcnt vmcnt(0)"
                 : "=v"(old) : "v"(p), "v"(v) : "memory");
    return old;
}
static __device__ __forceinline__ void atom_add_l2(unsigned* p, unsigned v) {
    asm volatile("global_atomic_add %0, %1, off" :: "v"(p), "v"(v) : "memory");
}
static __device__ __forceinline__ void vm_drain_schedfence() {
    asm volatile("s_waitcnt vmcnt(0)" ::: "memory");
    __builtin_amdgcn_sched_barrier(0);
}

// ---------------------------------------------------------------------------
__global__ __launch_bounds__(256) void cvt_bf16(
    const float* __restrict__ in, unsigned short* __restrict__ out, int n4)
{
    int i = blockIdx.x * 256 + threadIdx.x;
    if (i < n4) {
        float4 v = ((const float4*)in)[i];
        ushort4 o;
        o.x = f2bf(v.x); o.y = f2bf(v.y); o.z = f2bf(v.z); o.w = f2bf(v.w);
        ((ushort4*)out)[i] = o;
    }
}

// ---------------------------------------------------------------------------
template<int ROWS, int COLS>
__global__ __launch_bounds__(256) void transpose_bf16(
    const float* __restrict__ W, unsigned short* __restrict__ WT)
{
    __shared__ float tl[32][33];
    const int tx = threadIdx.x, ty = threadIdx.y;   // block (32, 8)
    const int bx = blockIdx.x, by = blockIdx.y;
    #pragma unroll
    for (int i = 0; i < 4; ++i) {
        int r = by * 32 + ty + i * 8;
        int c = bx * 32 + tx;
        tl[ty + i * 8][tx] = W[(size_t)r * COLS + c];
    }
    __syncthreads();
    #pragma unroll
    for (int i = 0; i < 4; ++i) {
        int n = bx * 32 + ty + i * 8;
        int k = by * 32 + tx;
        WT[(size_t)n * ROWS + k] = f2bf(tl[tx][ty + i * 8]);
    }
}

// ---------------------------------------------------------------------------
// Precompute GEMM. INTERLEAVE=true (gate matrix): store col j<1024 at 2j,
// col>=1024 at 2(j-1024)+1  ->  (r,u) value pairs adjacent per unit col.
// ---------------------------------------------------------------------------
template<bool INTERLEAVE>
__global__ __launch_bounds__(256) void gemm_xproj(
    const unsigned short* __restrict__ A,    // [M][1024]
    const unsigned short* __restrict__ BT,   // [N][2048]
    unsigned short* __restrict__ C,          // [M][N]
    int N)
{
    __shared__ unsigned short Al[128][72];
    __shared__ unsigned short Bl[128][72];
    const int tid  = threadIdx.x;
    const int lane = tid & 63;
    const int wave = tid >> 6;
    const int l15  = lane & 15;
    const int kg   = lane >> 4;
    const int m0   = blockIdx.y * 128;
    const int n0   = blockIdx.x * 128;
    const int rowOff = (wave >> 1) * 64;
    const int colOff = (wave & 1) * 64;

    f4v acc[4][4];
    #pragma unroll
    for (int m = 0; m < 4; ++m)
        #pragma unroll
        for (int n = 0; n < 4; ++n) acc[m][n] = (f4v){0.f, 0.f, 0.f, 0.f};

    for (int k0 = 0; k0 < 1024; k0 += 64) {
        #pragma unroll
        for (int it = 0; it < 4; ++it) {
            int c = tid + it * 256;
            int r = c >> 3, off = (c & 7) * 8;
            *(s8v*)&Al[r][off] = *(const s8v*)(A + (size_t)(m0 + r) * 1024 + k0 + off);
            *(s8v*)&Bl[r][off] = *(const s8v*)(BT + (size_t)(n0 + r) * 2048 + k0 + off);
        }
        __syncthreads();
        #pragma unroll
        for (int ks = 0; ks < 2; ++ks) {
            s8v a[4], b[4];
            #pragma unroll
            for (int m = 0; m < 4; ++m)
                a[m] = *(const s8v*)&Al[rowOff + m * 16 + l15][ks * 32 + kg * 8];
            #pragma unroll
            for (int n = 0; n < 4; ++n)
                b[n] = *(const s8v*)&Bl[colOff + n * 16 + l15][ks * 32 + kg * 8];
            #pragma unroll
            for (int m = 0; m < 4; ++m)
                #pragma unroll
                for (int n = 0; n < 4; ++n)
                    acc[m][n] = __builtin_amdgcn_mfma_f32_16x16x32_bf16(a[m], b[n], acc[m][n], 0, 0, 0);
        }
        __syncthreads();
    }
    #pragma unroll
    for (int m = 0; m < 4; ++m)
        #pragma unroll
        for (int n = 0; n < 4; ++n)
            #pragma unroll
            for (int i = 0; i < 4; ++i) {
                int row = m0 + rowOff + m * 16 + kg * 4 + i;
                int col = n0 + colOff + n * 16 + l15;
                size_t off = INTERLEAVE
                    ? (size_t)row * N + ((col < 1024) ? col * 2 : (col - 1024) * 2 + 1)
                    : (size_t)row * N + col;
                C[off] = f2bf(acc[m][n][i]);
            }
}

// ---------------------------------------------------------------------------
// Persistent GRU, hierarchical barrier + aligned ownership.
// 512 blocks launched; each registers on its physical XCD (plain L2 atomic);
// first 8 per XCD become workers -> 64 workers, w = xcd*8 + rank.
// Worker w owns unit cols J = [w*16, w*16+16):
//   phase G: r_J and u_J (gate cols J and 1024+J), weights VGPR-pinned.
//            r*h -> rhb (bf16, sc0sc1). u, h stay in REGISTERS.
//   phase C: cand_J from rhb (all k) x LDS weights; h=u*h+(1-u)*c in regs;
//            write hb (bf16, sc0sc1) + out.
// Barrier: local L2 add -> 8th arrival reps to LLC counter (sc1, 8-wide),
// publishes local L2 go-flag; peers poll locally. Data NEVER relies on L2.
// ---------------------------------------------------------------------------
__global__ __launch_bounds__(256, 2) void gru_hier(
    const unsigned short* __restrict__ WgT,   // [2048][2048] bf16
    const unsigned short* __restrict__ WcT,   // [1024][2048] bf16
    const unsigned short* __restrict__ Xg2,   // [B*T][2048] bf16, (r,u) interleaved
    const unsigned short* __restrict__ Xcb,   // [B*T][1024] bf16
    const float* __restrict__ bg,             // [2048]
    const float* __restrict__ bc,             // [1024]
    unsigned short* __restrict__ hb,          // [32][1024] bf16
    unsigned short* __restrict__ rhb,         // [32][1024] bf16
    float* __restrict__ out,                  // [B][T][U] f32
    unsigned* __restrict__ bar)
{
    __shared__ float redg[4][32][32];              // 16 KB (G); C uses first 8 KB
    __shared__ unsigned short wc_l[16 * 1024];     // 32 KB
    __shared__ int rank_sh;
    const int tid  = threadIdx.x;
    const int lane = tid & 63;
    const int wave = tid >> 6;
    const int l15  = lane & 15;
    const int kg   = lane >> 4;

    int xcd;
    asm volatile("s_getreg_b32 %0, hwreg(HW_REG_XCC_ID)" : "=s"(xcd));
    xcd &= 7;
    unsigned* lcnt = bar + 64  + xcd * 32;    // XCD-local lines (128 B apart)
    unsigned* lgo  = bar + 384 + xcd * 32;
    unsigned* lreg = bar + 704 + xcd * 32;
    unsigned* gcnt = bar;                     // LLC line

    if (tid == 0) rank_sh = (int)atom_add_ret_l2(lreg, 1u);
    __syncthreads();
    const int rank = rank_sh;
    if (rank >= 8) return;
    const int w = xcd * 8 + rank;
    const int J = w * 16;

    // ---- cand weights (16 cols, recurrent k) -> LDS, XOR-swizzled ----
    #pragma unroll
    for (int it = 0; it < 8; ++it) {
        int c   = tid + it * 256;
        int col = c >> 7;
        int k   = (c & 127) * 8;
        s8v wv = *(const s8v*)(WcT + (size_t)(J + col) * 2048 + 1024 + k);
        *(s8v*)&wc_l[col * 1024 + (k ^ ((col & 7) << 3))] = wv;
    }
    // ---- gate weights (r cols J, u cols 1024+J) -> pinned VGPRs ----
    const int kb = wave * 256;
    s8v bgf[2][8];
    #pragma unroll
    for (int kk = 0; kk < 8; ++kk) {
        bgf[0][kk] = ld_b128_pin(WgT + (size_t)(J + l15) * 2048 + 1024 + kb + kk * 32 + kg * 8);
        bgf[1][kk] = ld_b128_pin(WgT + (size_t)(1024 + J + l15) * 2048 + 1024 + kb + kk * 32 + kg * 8);
    }
    vm_drain_schedfence();

    // epilogue mapping: 2 adjacent cols x 1 batch per thread (32 b x 16 c)
    const int b  = tid >> 3;                  // 0..31
    const int c0 = (tid & 7) * 2;             // 0,2,..,14
    const float2 bgr = { bg[J + c0],        bg[J + c0 + 1] };
    const float2 bgu = { bg[1024 + J + c0], bg[1024 + J + c0 + 1] };
    const float2 bcp = { bc[J + c0],        bc[J + c0 + 1] };

    __syncthreads();                          // wc_l ready

    auto hbar = [&](unsigned ph) {
        asm volatile("s_waitcnt vmcnt(0)" ::: "memory");   // sc1 stores at LLC
        __syncthreads();
        if (tid == 0) {
            unsigned old = atom_add_ret_l2(lcnt, 1u);
            if (((old + 1) & 7) == 0) {       // 8th local arrival -> rep
                __hip_atomic_fetch_add(gcnt, 1u, __ATOMIC_RELAXED, __HIP_MEMORY_SCOPE_AGENT);
                while (__hip_atomic_load(gcnt, __ATOMIC_RELAXED, __HIP_MEMORY_SCOPE_AGENT) < 8u * ph)
                    __builtin_amdgcn_s_sleep(1);
                atom_add_l2(lgo, 1u);
            } else {
                while (atom_add_ret_l2(lgo, 0u) < ph)
                    __builtin_amdgcn_s_sleep(1);
            }
        }
        __syncthreads();
    };

    float h0 = 0.f, h1 = 0.f;                 // own h (register-resident)
    float u0 = 0.f, u1 = 0.f;

    for (int t = 0; t < TT; ++t) {
        const size_t bt = (size_t)b * TT + t;
        // ================= phase G: r_J, u_J =================
        ushort4 xgp = *(const ushort4*)(Xg2 + bt * 2048 + (size_t)(J + c0) * 2);
        unsigned xcp = *(const unsigned*)(Xcb + bt * 1024 + J + c0);

        s8v a[2][8];
        #pragma unroll
        for (int m = 0; m < 2; ++m)
            #pragma unroll
            for (int kk = 0; kk < 8; ++kk)
                a[m][kk] = ld_b128_sc(hb + (size_t)(m * 16 + l15) * 1024 + kb + kk * 32 + kg * 8);
        vm_drain_schedfence();

        f4v acc[2][2];
        #pragma unroll
        for (int m = 0; m < 2; ++m)
            #pragma unroll
            for (int n = 0; n < 2; ++n) acc[m][n] = (f4v){0.f, 0.f, 0.f, 0.f};
        #pragma unroll
        for (int kk = 0; kk < 8; ++kk)
            #pragma unroll
            for (int m = 0; m < 2; ++m)
                #pragma unroll
                for (int n = 0; n < 2; ++n)
                    acc[m][n] = __builtin_amdgcn_mfma_f32_16x16x32_bf16(a[m][kk], bgf[n][kk], acc[m][n], 0, 0, 0);

        #pragma unroll
        for (int m = 0; m < 2; ++m)
            #pragma unroll
            for (int n = 0; n < 2; ++n)
                #pragma unroll
                for (int i = 0; i < 4; ++i)
                    redg[wave][m * 16 + kg * 4 + i][n * 16 + l15] = acc[m][n][i];
        __syncthreads();

        {
            float2 pr = {0.f, 0.f}, pu = {0.f, 0.f};
            #pragma unroll
            for (int wv = 0; wv < 4; ++wv) {
                float2 p = *(const float2*)&redg[wv][b][c0];
                float2 q = *(const float2*)&redg[wv][b][16 + c0];
                pr.x += p.x; pr.y += p.y;
                pu.x += q.x; pu.y += q.y;
            }
            pr.x += bf2f(xgp.x) + bgr.x;  pu.x += bf2f(xgp.y) + bgu.x;
            pr.y += bf2f(xgp.z) + bgr.y;  pu.y += bf2f(xgp.w) + bgu.y;
            float r0 = 1.f / (1.f + __expf(-pr.x));
            float r1 = 1.f / (1.f + __expf(-pr.y));
            u0 = 1.f / (1.f + __expf(-pu.x));
            u1 = 1.f / (1.f + __expf(-pu.y));
            unsigned pk = (unsigned)f2bf(r0 * h0) | ((unsigned)f2bf(r1 * h1) << 16);
            st_b32_sc(rhb + (size_t)b * 1024 + J + c0, pk);
        }
        hbar((unsigned)(2 * t + 1));

        // ================= phase C: cand_J + update =================
        s8v ac[2][8];
        #pragma unroll
        for (int m = 0; m < 2; ++m)
            #pragma unroll
            for (int kk = 0; kk < 8; ++kk)
                ac[m][kk] = ld_b128_sc(rhb + (size_t)(m * 16 + l15) * 1024 + kb + kk * 32 + kg * 8);
        vm_drain_schedfence();

        f4v acc2[2];
        acc2[0] = (f4v){0.f, 0.f, 0.f, 0.f};
        acc2[1] = (f4v){0.f, 0.f, 0.f, 0.f};
        #pragma unroll
        for (int kk = 0; kk < 8; ++kk) {
            int k = kb + kk * 32 + kg * 8;
            s8v bcf = *(const s8v*)&wc_l[l15 * 1024 + (k ^ ((l15 & 7) << 3))];
            #pragma unroll
            for (int m = 0; m < 2; ++m)
                acc2[m] = __builtin_amdgcn_mfma_f32_16x16x32_bf16(ac[m][kk], bcf, acc2[m], 0, 0, 0);
        }
        float* redc = (float*)redg;           // [4][32][16]
        #pragma unroll
        for (int m = 0; m < 2; ++m)
            #pragma unroll
            for (int i = 0; i < 4; ++i)
                redc[((size_t)wave * 32 + m * 16 + kg * 4 + i) * 16 + l15] = acc2[m][i];
        __syncthreads();

        {
            float2 pc = {0.f, 0.f};
            #pragma unroll
            for (int wv = 0; wv < 4; ++wv) {
                float2 p = *(const float2*)&redc[((size_t)wv * 32 + b) * 16 + c0];
                pc.x += p.x; pc.y += p.y;
            }
            float cv0 = pc.x + bf2f((unsigned short)(xcp & 0xffff)) + bcp.x;
            float cv1 = pc.y + bf2f((unsigned short)(xcp >> 16)) + bcp.y;
            cv0 = fminf(fmaxf(cv0, -15.f), 15.f);
            cv1 = fminf(fmaxf(cv1, -15.f), 15.f);
            float e0 = __expf(2.f * cv0), e1 = __expf(2.f * cv1);
            float t0 = (e0 - 1.f) / (e0 + 1.f);
            float t1 = (e1 - 1.f) / (e1 + 1.f);
            h0 = u0 * h0 + (1.f - u0) * t0;
            h1 = u1 * h1 + (1.f - u1) * t1;
            st_b32_sc(hb + (size_t)b * 1024 + J + c0,
                      (unsigned)f2bf(h0) | ((unsigned)f2bf(h1) << 16));
            *(float2*)(out + bt * 1024 + J + c0) = make_float2(h0, h1);
        }
        hbar((unsigned)(2 * t + 2));
    }
}

// ===========================================================================
// Fallback per-step kernels (round-2, verified) — used only if ws too small.
// ===========================================================================
__global__ __launch_bounds__(256) void gru_gates2(
    const unsigned short* __restrict__ hb, const unsigned short* __restrict__ WgT,
    const unsigned short* __restrict__ Xgb, const float* __restrict__ bg,
    const float* __restrict__ h, unsigned short* __restrict__ rhb,
    float* __restrict__ ubuf, int t)
{
    __shared__ unsigned short hb_l[32][1032];
    __shared__ unsigned short Wl[16][1032];
    __shared__ float red[4][32][16];
    const int tid = threadIdx.x, lane = tid & 63, wave = tid >> 6;
    const int l15 = lane & 15, kg = lane >> 4;
    const int j0 = blockIdx.x * 16;
    #pragma unroll
    for (int it = 0; it < 16; ++it) {
        int c = tid + it * 256; int r = c >> 7, off = (c & 127) * 8;
        *(s8v*)&hb_l[r][off] = *(const s8v*)(hb + (size_t)r * 1024 + off);
    }
    #pragma unroll
    for (int it = 0; it < 8; ++it) {
        int c = tid + it * 256; int r = c >> 7, off = (c & 127) * 8;
        *(s8v*)&Wl[r][off] = *(const s8v*)(WgT + (size_t)(j0 + r) * 2048 + 1024 + off);
    }
    __syncthreads();
    f4v acc0 = (f4v){0.f,0.f,0.f,0.f}, acc1 = (f4v){0.f,0.f,0.f,0.f};
    const int kbase = wave * 256;
    #pragma unroll
    for (int kk = 0; kk < 8; ++kk) {
        int k = kbase + kk * 32 + kg * 8;
        s8v a0 = *(const s8v*)&hb_l[l15][k];
        s8v a1 = *(const s8v*)&hb_l[16 + l15][k];
        s8v bv = *(const s8v*)&Wl[l15][k];
        acc0 = __builtin_amdgcn_mfma_f32_16x16x32_bf16(a0, bv, acc0, 0, 0, 0);
        acc1 = __builtin_amdgcn_mfma_f32_16x16x32_bf16(a1, bv, acc1, 0, 0, 0);
    }
    #pragma unroll
    for (int i = 0; i < 4; ++i) {
        red[wave][kg * 4 + i][l15] = acc0[i];
        red[wave][16 + kg * 4 + i][l15] = acc1[i];
    }
    __syncthreads();
    for (int e = tid; e < 512; e += 256) {
        int b = e >> 4, col = e & 15;
        int j = j0 + col;
        float pre = red[0][b][col] + red[1][b][col] + red[2][b][col] + red[3][b][col];
        pre += bf2f(Xgb[((size_t)b * TT + t) * 2048 + j]) + bg[j];
        float s = 1.f / (1.f + __expf(-pre));
        if (j < UU) rhb[b * UU + j] = f2bf(s * h[b * UU + j]);
        else        ubuf[b * UU + (j - UU)] = s;
    }
}

__global__ __launch_bounds__(256) void gru_cand2(
    const unsigned short* __restrict__ rhb, const unsigned short* __restrict__ WcT,
    const unsigned short* __restrict__ Xcb, const float* __restrict__ bc,
    const float* __restrict__ ubuf, float* __restrict__ h,
    unsigned short* __restrict__ hb, float* __restrict__ out, int t)
{
    __shared__ unsigned short rh_l[32][1032];
    __shared__ unsigned short Wl[16][1032];
    __shared__ float red[4][32][16];
    const int tid = threadIdx.x, lane = tid & 63, wave = tid >> 6;
    const int l15 = lane & 15, kg = lane >> 4;
    const int j0 = blockIdx.x * 16;
    #pragma unroll
    for (int it = 0; it < 16; ++it) {
        int c = tid + it * 256; int r = c >> 7, off = (c & 127) * 8;
        *(s8v*)&rh_l[r][off] = *(const s8v*)(rhb + (size_t)r * 1024 + off);
    }
    #pragma unroll
    for (int it = 0; it < 8; ++it) {
        int c = tid + it * 256; int r = c >> 7, off = (c & 127) * 8;
        *(s8v*)&Wl[r][off] = *(const s8v*)(WcT + (size_t)(j0 + r) * 2048 + 1024 + off);
    }
    __syncthreads();
    f4v acc0 = (f4v){0.f,0.f,0.f,0.f}, acc1 = (f4v){0.f,0.f,0.f,0.f};
    const int kbase = wave * 256;
    #pragma unroll
    for (int kk = 0; kk < 8; ++kk) {
        int k = kbase + kk * 32 + kg * 8;
        s8v a0 = *(const s8v*)&rh_l[l15][k];
        s8v a1 = *(const s8v*)&rh_l[16 + l15][k];
        s8v bv = *(const s8v*)&Wl[l15][k];
        acc0 = __builtin_amdgcn_mfma_f32_16x16x32_bf16(a0, bv, acc0, 0, 0, 0);
        acc1 = __builtin_amdgcn_mfma_f32_16x16x32_bf16(a1, bv, acc1, 0, 0, 0);
    }
    #pragma unroll
    for (int i = 0; i < 4; ++i) {
        red[wave][kg * 4 + i][l15] = acc0[i];
        red[wave][16 + kg * 4 + i][l15] = acc1[i];
    }
    __syncthreads();
    for (int e = tid; e < 512; e += 256) {
        int b = e >> 4, col = e & 15;
        int j = j0 + col;
        float pre = red[0][b][col] + red[1][b][col] + red[2][b][col] + red[3][b][col];
        pre += bf2f(Xcb[((size_t)b * TT + t) * 1024 + j]) + bc[j];
        float cv = tanhf(pre);
        float u  = ubuf[b * UU + j];
        float hvv = h[b * UU + j];
        float hn = u * hvv + (1.f - u) * cv;
        h[b * UU + j]  = hn;
        hb[b * UU + j] = f2bf(hn);
        out[((size_t)b * TT + t) * UU + j] = hn;
    }
}

// ===========================================================================
extern "C" void kernel_launch(void* const* d_in, const int* in_sizes, int n_in,
                              void* d_out, int out_size, void* d_ws, size_t ws_size,
                              hipStream_t stream) {
    const float* x  = (const float*)d_in[0];
    const float* Wg = (const float*)d_in[1];
    const float* bg = (const float*)d_in[2];
    const float* Wc = (const float*)d_in[3];
    const float* bc = (const float*)d_in[4];
    float* out = (float*)d_out;

    const size_t XB_B  = (size_t)BB * TT * FF * 2;
    const size_t WGT_B = (size_t)2 * UU * (FF + UU) * 2;
    const size_t WCT_B = (size_t)UU * (FF + UU) * 2;
    const size_t XG_B  = (size_t)BB * TT * 2 * UU * 2;
    const size_t XC_B  = (size_t)BB * TT * UU * 2;
    const size_t H_B   = (size_t)BB * UU * 4;
    const size_t HB_B  = (size_t)BB * UU * 2;
    const size_t BAR_B = 4096;
    const size_t NEED  = XB_B + WGT_B + WCT_B + XG_B + XC_B + H_B + HB_B * 2 + H_B + BAR_B;

    char* p = (char*)d_ws;
    unsigned short* xb  = (unsigned short*)p;            p += XB_B;
    unsigned short* WgT = (unsigned short*)p;            p += WGT_B;
    unsigned short* WcT = (unsigned short*)p;            p += WCT_B;
    unsigned short* Xgb = (unsigned short*)p;            p += XG_B;   // interleaved for persistent
    unsigned short* Xcb = (unsigned short*)p;            p += XC_B;
    float*          h   = (float*)p;                     p += H_B;   // fallback only
    unsigned short* hb  = (unsigned short*)p;            p += HB_B;
    unsigned short* rhb = (unsigned short*)p;            p += HB_B;
    float*          ub  = (float*)p;                     p += H_B;   // fallback only
    unsigned*       bar = (unsigned*)p;                  p += BAR_B;

    const bool persistent = (ws_size >= NEED);

    // ---- one-time prep ----
    cvt_bf16<<<(BB * TT * FF / 4 + 255) / 256, 256, 0, stream>>>(x, xb, BB * TT * FF / 4);
    transpose_bf16<FF + UU, 2 * UU><<<dim3(64, 64), dim3(32, 8), 0, stream>>>(Wg, WgT);
    transpose_bf16<FF + UU, UU>    <<<dim3(32, 64), dim3(32, 8), 0, stream>>>(Wc, WcT);
    if (persistent)
        gemm_xproj<true><<<dim3(2 * UU / 128, BB * TT / 128), 256, 0, stream>>>(xb, WgT, Xgb, 2 * UU);
    else
        gemm_xproj<false><<<dim3(2 * UU / 128, BB * TT / 128), 256, 0, stream>>>(xb, WgT, Xgb, 2 * UU);
    gemm_xproj<false><<<dim3(UU / 128, BB * TT / 128), 256, 0, stream>>>(xb, WcT, Xcb, UU);
    hipMemsetAsync(h,   0, H_B,   stream);
    hipMemsetAsync(hb,  0, HB_B,  stream);
    hipMemsetAsync(bar, 0, BAR_B, stream);

    if (persistent) {
        gru_hier<<<GRID, 256, 0, stream>>>(WgT, WcT, Xgb, Xcb, bg, bc,
                                           hb, rhb, out, bar);
    } else {
        for (int t = 0; t < TT; ++t) {
            gru_gates2<<<128, 256, 0, stream>>>(hb, WgT, Xgb, bg, h, rhb, ub, t);
            gru_cand2 <<< 64, 256, 0, stream>>>(rhb, WcT, Xcb, bc, ub, h, hb, out, t);
        }
    }
}

// Round 11
// 5765.860 us; speedup vs baseline: 1.4563x; 1.1174x over previous
//
#include <hip/hip_runtime.h>
#include <math.h>

#define BB 32
#define TT 512
#define FF 1024
#define UU 1024
#define NBLK 64

typedef __attribute__((ext_vector_type(8))) short s8v;    // 8 x bf16 (4 VGPR)
typedef __attribute__((ext_vector_type(4))) float f4v;    // 4 x f32

static __device__ __forceinline__ unsigned short f2bf(float f) {
    unsigned int u = __builtin_bit_cast(unsigned int, f);
    u += 0x7fff + ((u >> 16) & 1);          // RNE
    return (unsigned short)(u >> 16);
}
static __device__ __forceinline__ float bf2f(unsigned short b) {
    unsigned int u = ((unsigned int)b) << 16;
    return __builtin_bit_cast(float, u);
}

// ---- PROVEN data path (R5/R7/R10): device-coherent sc0 sc1, fence-free ----
static __device__ __forceinline__ s8v ld_b128_sc(const void* p) {
    s8v r;
    asm volatile("global_load_dwordx4 %0, %1, off sc0 sc1" : "=v"(r) : "v"(p));
    return r;
}
static __device__ __forceinline__ void st_b32_sc(void* p, unsigned int v) {
    asm volatile("global_store_dword %0, %1, off sc0 sc1" :: "v"(p), "v"(v));
}
static __device__ __forceinline__ unsigned ld_u32_sc(const unsigned* p) {
    unsigned r;
    asm volatile("global_load_dword %0, %1, off sc0 sc1\n\ts_waitcnt vmcnt(0)"
                 : "=v"(r) : "v"(p) : "memory");
    return r;
}
// opaque plain load (un-rematerializable): pins weights in VGPRs
static __device__ __forceinline__ s8v ld_b128_pin(const void* p) {
    s8v r;
    asm volatile("global_load_dwordx4 %0, %1, off" : "=v"(r) : "v"(p));
    return r;
}
static __device__ __forceinline__ void vm_drain_schedfence() {
    asm volatile("s_waitcnt vmcnt(0)" ::: "memory");
    __builtin_amdgcn_sched_barrier(0);
}

// ---------------------------------------------------------------------------
__global__ __launch_bounds__(256) void cvt_bf16(
    const float* __restrict__ in, unsigned short* __restrict__ out, int n4)
{
    int i = blockIdx.x * 256 + threadIdx.x;
    if (i < n4) {
        float4 v = ((const float4*)in)[i];
        ushort4 o;
        o.x = f2bf(v.x); o.y = f2bf(v.y); o.z = f2bf(v.z); o.w = f2bf(v.w);
        ((ushort4*)out)[i] = o;
    }
}

// ---------------------------------------------------------------------------
template<int ROWS, int COLS>
__global__ __launch_bounds__(256) void transpose_bf16(
    const float* __restrict__ W, unsigned short* __restrict__ WT)
{
    __shared__ float tl[32][33];
    const int tx = threadIdx.x, ty = threadIdx.y;   // block (32, 8)
    const int bx = blockIdx.x, by = blockIdx.y;
    #pragma unroll
    for (int i = 0; i < 4; ++i) {
        int r = by * 32 + ty + i * 8;
        int c = bx * 32 + tx;
        tl[ty + i * 8][tx] = W[(size_t)r * COLS + c];
    }
    __syncthreads();
    #pragma unroll
    for (int i = 0; i < 4; ++i) {
        int n = bx * 32 + ty + i * 8;
        int k = by * 32 + tx;
        WT[(size_t)n * ROWS + k] = f2bf(tl[tx][ty + i * 8]);
    }
}

// ---------------------------------------------------------------------------
// Precompute GEMM. INTERLEAVE=true (gate matrix): store col j<1024 at 2j,
// col>=1024 at 2(j-1024)+1  ->  (r,u) value pairs adjacent per unit col.
// ---------------------------------------------------------------------------
template<bool INTERLEAVE>
__global__ __launch_bounds__(256) void gemm_xproj(
    const unsigned short* __restrict__ A,    // [M][1024]
    const unsigned short* __restrict__ BT,   // [N][2048]
    unsigned short* __restrict__ C,          // [M][N]
    int N)
{
    __shared__ unsigned short Al[128][72];
    __shared__ unsigned short Bl[128][72];
    const int tid  = threadIdx.x;
    const int lane = tid & 63;
    const int wave = tid >> 6;
    const int l15  = lane & 15;
    const int kg   = lane >> 4;
    const int m0   = blockIdx.y * 128;
    const int n0   = blockIdx.x * 128;
    const int rowOff = (wave >> 1) * 64;
    const int colOff = (wave & 1) * 64;

    f4v acc[4][4];
    #pragma unroll
    for (int m = 0; m < 4; ++m)
        #pragma unroll
        for (int n = 0; n < 4; ++n) acc[m][n] = (f4v){0.f, 0.f, 0.f, 0.f};

    for (int k0 = 0; k0 < 1024; k0 += 64) {
        #pragma unroll
        for (int it = 0; it < 4; ++it) {
            int c = tid + it * 256;
            int r = c >> 3, off = (c & 7) * 8;
            *(s8v*)&Al[r][off] = *(const s8v*)(A + (size_t)(m0 + r) * 1024 + k0 + off);
            *(s8v*)&Bl[r][off] = *(const s8v*)(BT + (size_t)(n0 + r) * 2048 + k0 + off);
        }
        __syncthreads();
        #pragma unroll
        for (int ks = 0; ks < 2; ++ks) {
            s8v a[4], b[4];
            #pragma unroll
            for (int m = 0; m < 4; ++m)
                a[m] = *(const s8v*)&Al[rowOff + m * 16 + l15][ks * 32 + kg * 8];
            #pragma unroll
            for (int n = 0; n < 4; ++n)
                b[n] = *(const s8v*)&Bl[colOff + n * 16 + l15][ks * 32 + kg * 8];
            #pragma unroll
            for (int m = 0; m < 4; ++m)
                #pragma unroll
                for (int n = 0; n < 4; ++n)
                    acc[m][n] = __builtin_amdgcn_mfma_f32_16x16x32_bf16(a[m], b[n], acc[m][n], 0, 0, 0);
        }
        __syncthreads();
    }
    #pragma unroll
    for (int m = 0; m < 4; ++m)
        #pragma unroll
        for (int n = 0; n < 4; ++n)
            #pragma unroll
            for (int i = 0; i < 4; ++i) {
                int row = m0 + rowOff + m * 16 + kg * 4 + i;
                int col = n0 + colOff + n * 16 + l15;
                size_t off = INTERLEAVE
                    ? (size_t)row * N + ((col < 1024) ? col * 2 : (col - 1024) * 2 + 1)
                    : (size_t)row * N + col;
                C[off] = f2bf(acc[m][n][i]);
            }
}

// ---------------------------------------------------------------------------
// Persistent GRU: flat 64 blocks, aligned ownership, SLOT barrier.
// Block w owns unit cols J = [w*16, w*16+16):
//   phase G: r_J, u_J (gate weights VGPR-pinned); r*h -> rhb (bf16 sc0sc1);
//            u, h stay in registers.
//   phase C: cand_J from rhb x LDS weights; h = u*h+(1-u)*c in regs;
//            write hb (bf16 sc0sc1) + out.
// Slot barrier: arrive = ONE plain sc1 store to bar[w] (no RMW contention);
// wait = wave-parallel poll (lane i loads bar[i], __all(>=epoch)).
// ---------------------------------------------------------------------------
__global__ __launch_bounds__(256, 1) void gru_slot(
    const unsigned short* __restrict__ WgT,   // [2048][2048] bf16
    const unsigned short* __restrict__ WcT,   // [1024][2048] bf16
    const unsigned short* __restrict__ Xg2,   // [B*T][2048] bf16, (r,u) interleaved
    const unsigned short* __restrict__ Xcb,   // [B*T][1024] bf16
    const float* __restrict__ bg,             // [2048]
    const float* __restrict__ bc,             // [1024]
    unsigned short* __restrict__ hb,          // [32][1024] bf16
    unsigned short* __restrict__ rhb,         // [32][1024] bf16
    float* __restrict__ out,                  // [B][T][U] f32
    unsigned* __restrict__ bar)               // slots [64]
{
    __shared__ float redg[4][32][32];              // 16 KB (G); C reuses 8 KB
    __shared__ unsigned short wc_l[16 * 1024];     // 32 KB
    const int tid  = threadIdx.x;
    const int lane = tid & 63;
    const int wave = tid >> 6;
    const int l15  = lane & 15;
    const int kg   = lane >> 4;
    const int w    = blockIdx.x;
    const int J    = w * 16;
    const int kb   = wave * 256;

    // ---- cand weights (16 cols, recurrent k) -> LDS, XOR-swizzled ----
    #pragma unroll
    for (int it = 0; it < 8; ++it) {
        int c   = tid + it * 256;
        int col = c >> 7;
        int k   = (c & 127) * 8;
        s8v wv = *(const s8v*)(WcT + (size_t)(J + col) * 2048 + 1024 + k);
        *(s8v*)&wc_l[col * 1024 + (k ^ ((col & 7) << 3))] = wv;
    }
    // ---- gate weights (r cols J, u cols 1024+J) -> pinned VGPRs ----
    s8v bgf[2][8];
    #pragma unroll
    for (int kk = 0; kk < 8; ++kk) {
        bgf[0][kk] = ld_b128_pin(WgT + (size_t)(J + l15) * 2048 + 1024 + kb + kk * 32 + kg * 8);
        bgf[1][kk] = ld_b128_pin(WgT + (size_t)(1024 + J + l15) * 2048 + 1024 + kb + kk * 32 + kg * 8);
    }
    vm_drain_schedfence();

    // epilogue mapping: 2 adjacent cols x 1 batch per thread (32 b x 16 c)
    const int b  = tid >> 3;                  // 0..31
    const int c0 = (tid & 7) * 2;             // 0,2,..,14
    const float2 bgr = { bg[J + c0],        bg[J + c0 + 1] };
    const float2 bgu = { bg[1024 + J + c0], bg[1024 + J + c0 + 1] };
    const float2 bcp = { bc[J + c0],        bc[J + c0 + 1] };

    __syncthreads();                          // wc_l ready

    // slot barrier: arrive (one store) + wave-parallel wait
    auto sbar = [&](unsigned ph) {
        asm volatile("s_waitcnt vmcnt(0)" ::: "memory");   // data at LLC first
        __syncthreads();
        if (wave == 0) {
            if (lane == 0) st_b32_sc(bar + w, ph);
            unsigned v;
            do {
                v = ld_u32_sc(bar + lane);
            } while (!__all((int)(v >= ph)));
        }
        __syncthreads();
    };

    float h0 = 0.f, h1 = 0.f;                 // own h (register-resident)
    float u0 = 0.f, u1 = 0.f;

    for (int t = 0; t < TT; ++t) {
        const size_t bt = (size_t)b * TT + t;
        // ================= phase G: r_J, u_J =================
        ushort4 xgp = *(const ushort4*)(Xg2 + bt * 2048 + (size_t)(J + c0) * 2);
        unsigned xcp = *(const unsigned*)(Xcb + bt * 1024 + J + c0);

        s8v a[2][8];
        #pragma unroll
        for (int m = 0; m < 2; ++m)
            #pragma unroll
            for (int kk = 0; kk < 8; ++kk)
                a[m][kk] = ld_b128_sc(hb + (size_t)(m * 16 + l15) * 1024 + kb + kk * 32 + kg * 8);
        vm_drain_schedfence();

        f4v acc[2][2];
        #pragma unroll
        for (int m = 0; m < 2; ++m)
            #pragma unroll
            for (int n = 0; n < 2; ++n) acc[m][n] = (f4v){0.f, 0.f, 0.f, 0.f};
        #pragma unroll
        for (int kk = 0; kk < 8; ++kk)
            #pragma unroll
            for (int m = 0; m < 2; ++m)
                #pragma unroll
                for (int n = 0; n < 2; ++n)
                    acc[m][n] = __builtin_amdgcn_mfma_f32_16x16x32_bf16(a[m][kk], bgf[n][kk], acc[m][n], 0, 0, 0);

        #pragma unroll
        for (int m = 0; m < 2; ++m)
            #pragma unroll
            for (int n = 0; n < 2; ++n)
                #pragma unroll
                for (int i = 0; i < 4; ++i)
                    redg[wave][m * 16 + kg * 4 + i][n * 16 + l15] = acc[m][n][i];
        __syncthreads();

        {
            float2 pr = {0.f, 0.f}, pu = {0.f, 0.f};
            #pragma unroll
            for (int wv = 0; wv < 4; ++wv) {
                float2 p = *(const float2*)&redg[wv][b][c0];
                float2 q = *(const float2*)&redg[wv][b][16 + c0];
                pr.x += p.x; pr.y += p.y;
                pu.x += q.x; pu.y += q.y;
            }
            pr.x += bf2f(xgp.x) + bgr.x;  pu.x += bf2f(xgp.y) + bgu.x;
            pr.y += bf2f(xgp.z) + bgr.y;  pu.y += bf2f(xgp.w) + bgu.y;
            float r0 = 1.f / (1.f + __expf(-pr.x));
            float r1 = 1.f / (1.f + __expf(-pr.y));
            u0 = 1.f / (1.f + __expf(-pu.x));
            u1 = 1.f / (1.f + __expf(-pu.y));
            unsigned pk = (unsigned)f2bf(r0 * h0) | ((unsigned)f2bf(r1 * h1) << 16);
            st_b32_sc(rhb + (size_t)b * 1024 + J + c0, pk);
        }
        sbar((unsigned)(2 * t + 1));

        // ================= phase C: cand_J + update =================
        s8v ac[2][8];
        #pragma unroll
        for (int m = 0; m < 2; ++m)
            #pragma unroll
            for (int kk = 0; kk < 8; ++kk)
                ac[m][kk] = ld_b128_sc(rhb + (size_t)(m * 16 + l15) * 1024 + kb + kk * 32 + kg * 8);
        vm_drain_schedfence();

        f4v acc2[2];
        acc2[0] = (f4v){0.f, 0.f, 0.f, 0.f};
        acc2[1] = (f4v){0.f, 0.f, 0.f, 0.f};
        #pragma unroll
        for (int kk = 0; kk < 8; ++kk) {
            int k = kb + kk * 32 + kg * 8;
            s8v bcf = *(const s8v*)&wc_l[l15 * 1024 + (k ^ ((l15 & 7) << 3))];
            #pragma unroll
            for (int m = 0; m < 2; ++m)
                acc2[m] = __builtin_amdgcn_mfma_f32_16x16x32_bf16(ac[m][kk], bcf, acc2[m], 0, 0, 0);
        }
        float* redc = (float*)redg;           // [4][32][16]
        #pragma unroll
        for (int m = 0; m < 2; ++m)
            #pragma unroll
            for (int i = 0; i < 4; ++i)
                redc[((size_t)wave * 32 + m * 16 + kg * 4 + i) * 16 + l15] = acc2[m][i];
        __syncthreads();

        {
            float2 pc = {0.f, 0.f};
            #pragma unroll
            for (int wv = 0; wv < 4; ++wv) {
                float2 p = *(const float2*)&redc[((size_t)wv * 32 + b) * 16 + c0];
                pc.x += p.x; pc.y += p.y;
            }
            float cv0 = pc.x + bf2f((unsigned short)(xcp & 0xffff)) + bcp.x;
            float cv1 = pc.y + bf2f((unsigned short)(xcp >> 16)) + bcp.y;
            cv0 = fminf(fmaxf(cv0, -15.f), 15.f);
            cv1 = fminf(fmaxf(cv1, -15.f), 15.f);
            float e0 = __expf(2.f * cv0), e1 = __expf(2.f * cv1);
            float t0 = (e0 - 1.f) / (e0 + 1.f);
            float t1 = (e1 - 1.f) / (e1 + 1.f);
            h0 = u0 * h0 + (1.f - u0) * t0;
            h1 = u1 * h1 + (1.f - u1) * t1;
            st_b32_sc(hb + (size_t)b * 1024 + J + c0,
                      (unsigned)f2bf(h0) | ((unsigned)f2bf(h1) << 16));
            *(float2*)(out + bt * 1024 + J + c0) = make_float2(h0, h1);
        }
        if (t + 1 < TT) sbar((unsigned)(2 * t + 2));
    }
}

// ===========================================================================
// Fallback per-step kernels (round-2, verified) — used only if ws too small.
// ===========================================================================
__global__ __launch_bounds__(256) void gru_gates2(
    const unsigned short* __restrict__ hb, const unsigned short* __restrict__ WgT,
    const unsigned short* __restrict__ Xgb, const float* __restrict__ bg,
    const float* __restrict__ h, unsigned short* __restrict__ rhb,
    float* __restrict__ ubuf, int t)
{
    __shared__ unsigned short hb_l[32][1032];
    __shared__ unsigned short Wl[16][1032];
    __shared__ float red[4][32][16];
    const int tid = threadIdx.x, lane = tid & 63, wave = tid >> 6;
    const int l15 = lane & 15, kg = lane >> 4;
    const int j0 = blockIdx.x * 16;
    #pragma unroll
    for (int it = 0; it < 16; ++it) {
        int c = tid + it * 256; int r = c >> 7, off = (c & 127) * 8;
        *(s8v*)&hb_l[r][off] = *(const s8v*)(hb + (size_t)r * 1024 + off);
    }
    #pragma unroll
    for (int it = 0; it < 8; ++it) {
        int c = tid + it * 256; int r = c >> 7, off = (c & 127) * 8;
        *(s8v*)&Wl[r][off] = *(const s8v*)(WgT + (size_t)(j0 + r) * 2048 + 1024 + off);
    }
    __syncthreads();
    f4v acc0 = (f4v){0.f,0.f,0.f,0.f}, acc1 = (f4v){0.f,0.f,0.f,0.f};
    const int kbase = wave * 256;
    #pragma unroll
    for (int kk = 0; kk < 8; ++kk) {
        int k = kbase + kk * 32 + kg * 8;
        s8v a0 = *(const s8v*)&hb_l[l15][k];
        s8v a1 = *(const s8v*)&hb_l[16 + l15][k];
        s8v bv = *(const s8v*)&Wl[l15][k];
        acc0 = __builtin_amdgcn_mfma_f32_16x16x32_bf16(a0, bv, acc0, 0, 0, 0);
        acc1 = __builtin_amdgcn_mfma_f32_16x16x32_bf16(a1, bv, acc1, 0, 0, 0);
    }
    #pragma unroll
    for (int i = 0; i < 4; ++i) {
        red[wave][kg * 4 + i][l15] = acc0[i];
        red[wave][16 + kg * 4 + i][l15] = acc1[i];
    }
    __syncthreads();
    for (int e = tid; e < 512; e += 256) {
        int b = e >> 4, col = e & 15;
        int j = j0 + col;
        float pre = red[0][b][col] + red[1][b][col] + red[2][b][col] + red[3][b][col];
        pre += bf2f(Xgb[((size_t)b * TT + t) * 2048 + j]) + bg[j];
        float s = 1.f / (1.f + __expf(-pre));
        if (j < UU) rhb[b * UU + j] = f2bf(s * h[b * UU + j]);
        else        ubuf[b * UU + (j - UU)] = s;
    }
}

__global__ __launch_bounds__(256) void gru_cand2(
    const unsigned short* __restrict__ rhb, const unsigned short* __restrict__ WcT,
    const unsigned short* __restrict__ Xcb, const float* __restrict__ bc,
    const float* __restrict__ ubuf, float* __restrict__ h,
    unsigned short* __restrict__ hb, float* __restrict__ out, int t)
{
    __shared__ unsigned short rh_l[32][1032];
    __shared__ unsigned short Wl[16][1032];
    __shared__ float red[4][32][16];
    const int tid = threadIdx.x, lane = tid & 63, wave = tid >> 6;
    const int l15 = lane & 15, kg = lane >> 4;
    const int j0 = blockIdx.x * 16;
    #pragma unroll
    for (int it = 0; it < 16; ++it) {
        int c = tid + it * 256; int r = c >> 7, off = (c & 127) * 8;
        *(s8v*)&rh_l[r][off] = *(const s8v*)(rhb + (size_t)r * 1024 + off);
    }
    #pragma unroll
    for (int it = 0; it < 8; ++it) {
        int c = tid + it * 256; int r = c >> 7, off = (c & 127) * 8;
        *(s8v*)&Wl[r][off] = *(const s8v*)(WcT + (size_t)(j0 + r) * 2048 + 1024 + off);
    }
    __syncthreads();
    f4v acc0 = (f4v){0.f,0.f,0.f,0.f}, acc1 = (f4v){0.f,0.f,0.f,0.f};
    const int kbase = wave * 256;
    #pragma unroll
    for (int kk = 0; kk < 8; ++kk) {
        int k = kbase + kk * 32 + kg * 8;
        s8v a0 = *(const s8v*)&rh_l[l15][k];
        s8v a1 = *(const s8v*)&rh_l[16 + l15][k];
        s8v bv = *(const s8v*)&Wl[l15][k];
        acc0 = __builtin_amdgcn_mfma_f32_16x16x32_bf16(a0, bv, acc0, 0, 0, 0);
        acc1 = __builtin_amdgcn_mfma_f32_16x16x32_bf16(a1, bv, acc1, 0, 0, 0);
    }
    #pragma unroll
    for (int i = 0; i < 4; ++i) {
        red[wave][kg * 4 + i][l15] = acc0[i];
        red[wave][16 + kg * 4 + i][l15] = acc1[i];
    }
    __syncthreads();
    for (int e = tid; e < 512; e += 256) {
        int b = e >> 4, col = e & 15;
        int j = j0 + col;
        float pre = red[0][b][col] + red[1][b][col] + red[2][b][col] + red[3][b][col];
        pre += bf2f(Xcb[((size_t)b * TT + t) * 1024 + j]) + bc[j];
        float cv = tanhf(pre);
        float u  = ubuf[b * UU + j];
        float hvv = h[b * UU + j];
        float hn = u * hvv + (1.f - u) * cv;
        h[b * UU + j]  = hn;
        hb[b * UU + j] = f2bf(hn);
        out[((size_t)b * TT + t) * UU + j] = hn;
    }
}

// ===========================================================================
extern "C" void kernel_launch(void* const* d_in, const int* in_sizes, int n_in,
                              void* d_out, int out_size, void* d_ws, size_t ws_size,
                              hipStream_t stream) {
    const float* x  = (const float*)d_in[0];
    const float* Wg = (const float*)d_in[1];
    const float* bg = (const float*)d_in[2];
    const float* Wc = (const float*)d_in[3];
    const float* bc = (const float*)d_in[4];
    float* out = (float*)d_out;

    const size_t XB_B  = (size_t)BB * TT * FF * 2;
    const size_t WGT_B = (size_t)2 * UU * (FF + UU) * 2;
    const size_t WCT_B = (size_t)UU * (FF + UU) * 2;
    const size_t XG_B  = (size_t)BB * TT * 2 * UU * 2;
    const size_t XC_B  = (size_t)BB * TT * UU * 2;
    const size_t H_B   = (size_t)BB * UU * 4;
    const size_t HB_B  = (size_t)BB * UU * 2;
    const size_t BAR_B = 4096;
    const size_t NEED  = XB_B + WGT_B + WCT_B + XG_B + XC_B + H_B + HB_B * 2 + H_B + BAR_B;

    char* p = (char*)d_ws;
    unsigned short* xb  = (unsigned short*)p;            p += XB_B;
    unsigned short* WgT = (unsigned short*)p;            p += WGT_B;
    unsigned short* WcT = (unsigned short*)p;            p += WCT_B;
    unsigned short* Xgb = (unsigned short*)p;            p += XG_B;   // interleaved for persistent
    unsigned short* Xcb = (unsigned short*)p;            p += XC_B;
    float*          h   = (float*)p;                     p += H_B;   // fallback only
    unsigned short* hb  = (unsigned short*)p;            p += HB_B;
    unsigned short* rhb = (unsigned short*)p;            p += HB_B;
    float*          ub  = (float*)p;                     p += H_B;   // fallback only
    unsigned*       bar = (unsigned*)p;                  p += BAR_B;

    const bool persistent = (ws_size >= NEED);

    // ---- one-time prep ----
    cvt_bf16<<<(BB * TT * FF / 4 + 255) / 256, 256, 0, stream>>>(x, xb, BB * TT * FF / 4);
    transpose_bf16<FF + UU, 2 * UU><<<dim3(64, 64), dim3(32, 8), 0, stream>>>(Wg, WgT);
    transpose_bf16<FF + UU, UU>    <<<dim3(32, 64), dim3(32, 8), 0, stream>>>(Wc, WcT);
    if (persistent)
        gemm_xproj<true><<<dim3(2 * UU / 128, BB * TT / 128), 256, 0, stream>>>(xb, WgT, Xgb, 2 * UU);
    else
        gemm_xproj<false><<<dim3(2 * UU / 128, BB * TT / 128), 256, 0, stream>>>(xb, WgT, Xgb, 2 * UU);
    gemm_xproj<false><<<dim3(UU / 128, BB * TT / 128), 256, 0, stream>>>(xb, WcT, Xcb, UU);
    hipMemsetAsync(h,   0, H_B,   stream);
    hipMemsetAsync(hb,  0, HB_B,  stream);
    hipMemsetAsync(bar, 0, BAR_B, stream);

    if (persistent) {
        gru_slot<<<NBLK, 256, 0, stream>>>(WgT, WcT, Xgb, Xcb, bg, bc,
                                           hb, rhb, out, bar);
    } else {
        for (int t = 0; t < TT; ++t) {
            gru_gates2<<<128, 256, 0, stream>>>(hb, WgT, Xgb, bg, h, rhb, ub, t);
            gru_cand2 <<< 64, 256, 0, stream>>>(rhb, WcT, Xcb, bc, ub, h, hb, out, t);
        }
    }
}

// Round 12
// 4669.776 us; speedup vs baseline: 1.7981x; 1.2347x over previous
//
#include <hip/hip_runtime.h>
#include <math.h>

#define BB 32
#define TT 512
#define FF 1024
#define UU 1024
#define NBLK 64

typedef __attribute__((ext_vector_type(8))) short s8v;    // 8 x bf16 (4 VGPR)
typedef __attribute__((ext_vector_type(4))) float f4v;    // 4 x f32

static __device__ __forceinline__ unsigned short f2bf(float f) {
    unsigned int u = __builtin_bit_cast(unsigned int, f);
    u += 0x7fff + ((u >> 16) & 1);          // RNE
    return (unsigned short)(u >> 16);
}
static __device__ __forceinline__ float bf2f(unsigned short b) {
    unsigned int u = ((unsigned int)b) << 16;
    return __builtin_bit_cast(float, u);
}

// ---- PROVEN data path (R5/R7/R10/R11): device-coherent sc0 sc1, fence-free ----
static __device__ __forceinline__ s8v ld_b128_sc(const void* p) {
    s8v r;
    asm volatile("global_load_dwordx4 %0, %1, off sc0 sc1" : "=v"(r) : "v"(p));
    return r;
}
static __device__ __forceinline__ void st_b32_sc(void* p, unsigned int v) {
    asm volatile("global_store_dword %0, %1, off sc0 sc1" :: "v"(p), "v"(v));
}
// opaque plain load (un-rematerializable): pins weights in VGPRs
static __device__ __forceinline__ s8v ld_b128_pin(const void* p) {
    s8v r;
    asm volatile("global_load_dwordx4 %0, %1, off" : "=v"(r) : "v"(p));
    return r;
}
static __device__ __forceinline__ void vm_drain_schedfence() {
    asm volatile("s_waitcnt vmcnt(0)" ::: "memory");
    __builtin_amdgcn_sched_barrier(0);
}

// ---------------------------------------------------------------------------
__global__ __launch_bounds__(256) void cvt_bf16(
    const float* __restrict__ in, unsigned short* __restrict__ out, int n4)
{
    int i = blockIdx.x * 256 + threadIdx.x;
    if (i < n4) {
        float4 v = ((const float4*)in)[i];
        ushort4 o;
        o.x = f2bf(v.x); o.y = f2bf(v.y); o.z = f2bf(v.z); o.w = f2bf(v.w);
        ((ushort4*)out)[i] = o;
    }
}

// ---------------------------------------------------------------------------
template<int ROWS, int COLS>
__global__ __launch_bounds__(256) void transpose_bf16(
    const float* __restrict__ W, unsigned short* __restrict__ WT)
{
    __shared__ float tl[32][33];
    const int tx = threadIdx.x, ty = threadIdx.y;   // block (32, 8)
    const int bx = blockIdx.x, by = blockIdx.y;
    #pragma unroll
    for (int i = 0; i < 4; ++i) {
        int r = by * 32 + ty + i * 8;
        int c = bx * 32 + tx;
        tl[ty + i * 8][tx] = W[(size_t)r * COLS + c];
    }
    __syncthreads();
    #pragma unroll
    for (int i = 0; i < 4; ++i) {
        int n = bx * 32 + ty + i * 8;
        int k = by * 32 + tx;
        WT[(size_t)n * ROWS + k] = f2bf(tl[tx][ty + i * 8]);
    }
}

// ---------------------------------------------------------------------------
// Precompute GEMM. INTERLEAVE=true (gate matrix): store col j<1024 at 2j,
// col>=1024 at 2(j-1024)+1  ->  (r,u) value pairs adjacent per unit col.
// ---------------------------------------------------------------------------
template<bool INTERLEAVE>
__global__ __launch_bounds__(256) void gemm_xproj(
    const unsigned short* __restrict__ A,    // [M][1024]
    const unsigned short* __restrict__ BT,   // [N][2048]
    unsigned short* __restrict__ C,          // [M][N]
    int N)
{
    __shared__ unsigned short Al[128][72];
    __shared__ unsigned short Bl[128][72];
    const int tid  = threadIdx.x;
    const int lane = tid & 63;
    const int wave = tid >> 6;
    const int l15  = lane & 15;
    const int kg   = lane >> 4;
    const int m0   = blockIdx.y * 128;
    const int n0   = blockIdx.x * 128;
    const int rowOff = (wave >> 1) * 64;
    const int colOff = (wave & 1) * 64;

    f4v acc[4][4];
    #pragma unroll
    for (int m = 0; m < 4; ++m)
        #pragma unroll
        for (int n = 0; n < 4; ++n) acc[m][n] = (f4v){0.f, 0.f, 0.f, 0.f};

    for (int k0 = 0; k0 < 1024; k0 += 64) {
        #pragma unroll
        for (int it = 0; it < 4; ++it) {
            int c = tid + it * 256;
            int r = c >> 3, off = (c & 7) * 8;
            *(s8v*)&Al[r][off] = *(const s8v*)(A + (size_t)(m0 + r) * 1024 + k0 + off);
            *(s8v*)&Bl[r][off] = *(const s8v*)(BT + (size_t)(n0 + r) * 2048 + k0 + off);
        }
        __syncthreads();
        #pragma unroll
        for (int ks = 0; ks < 2; ++ks) {
            s8v a[4], b[4];
            #pragma unroll
            for (int m = 0; m < 4; ++m)
                a[m] = *(const s8v*)&Al[rowOff + m * 16 + l15][ks * 32 + kg * 8];
            #pragma unroll
            for (int n = 0; n < 4; ++n)
                b[n] = *(const s8v*)&Bl[colOff + n * 16 + l15][ks * 32 + kg * 8];
            #pragma unroll
            for (int m = 0; m < 4; ++m)
                #pragma unroll
                for (int n = 0; n < 4; ++n)
                    acc[m][n] = __builtin_amdgcn_mfma_f32_16x16x32_bf16(a[m], b[n], acc[m][n], 0, 0, 0);
        }
        __syncthreads();
    }
    #pragma unroll
    for (int m = 0; m < 4; ++m)
        #pragma unroll
        for (int n = 0; n < 4; ++n)
            #pragma unroll
            for (int i = 0; i < 4; ++i) {
                int row = m0 + rowOff + m * 16 + kg * 4 + i;
                int col = n0 + colOff + n * 16 + l15;
                size_t off = INTERLEAVE
                    ? (size_t)row * N + ((col < 1024) ? col * 2 : (col - 1024) * 2 + 1)
                    : (size_t)row * N + col;
                C[off] = f2bf(acc[m][n][i]);
            }
}

// ---------------------------------------------------------------------------
// Persistent GRU: R11's aligned-ownership body + R5's proven barrier.
// Block w owns unit cols J = [w*16, w*16+16) for r, u, AND cand:
//   phase G: r_J, u_J (gate weights VGPR-pinned); r*h -> rhb (bf16 sc0sc1);
//            u, h stay in registers (no h/ub arrays at all).
//   phase C: cand_J from rhb x LDS weights; h = u*h+(1-u)*c in regs;
//            write hb (bf16 sc0sc1) + out.
// Barrier (R5-verified fastest): vmcnt drain -> relaxed agent fetch_add ->
// relaxed-load spin on ONE monotonic counter. No fences ever -> L2 warm.
// ---------------------------------------------------------------------------
__global__ __launch_bounds__(256, 1) void gru_fast(
    const unsigned short* __restrict__ WgT,   // [2048][2048] bf16
    const unsigned short* __restrict__ WcT,   // [1024][2048] bf16
    const unsigned short* __restrict__ Xg2,   // [B*T][2048] bf16, (r,u) interleaved
    const unsigned short* __restrict__ Xcb,   // [B*T][1024] bf16
    const float* __restrict__ bg,             // [2048]
    const float* __restrict__ bc,             // [1024]
    unsigned short* __restrict__ hb,          // [32][1024] bf16
    unsigned short* __restrict__ rhb,         // [32][1024] bf16
    float* __restrict__ out,                  // [B][T][U] f32
    unsigned* __restrict__ bar)               // [0] monotonic counter
{
    __shared__ float redg[4][32][32];              // 16 KB (G); C reuses 8 KB
    __shared__ unsigned short wc_l[16 * 1024];     // 32 KB
    const int tid  = threadIdx.x;
    const int lane = tid & 63;
    const int wave = tid >> 6;
    const int l15  = lane & 15;
    const int kg   = lane >> 4;
    const int w    = blockIdx.x;
    const int J    = w * 16;
    const int kb   = wave * 256;

    // ---- cand weights (16 cols, recurrent k) -> LDS, XOR-swizzled ----
    #pragma unroll
    for (int it = 0; it < 8; ++it) {
        int c   = tid + it * 256;
        int col = c >> 7;
        int k   = (c & 127) * 8;
        s8v wv = *(const s8v*)(WcT + (size_t)(J + col) * 2048 + 1024 + k);
        *(s8v*)&wc_l[col * 1024 + (k ^ ((col & 7) << 3))] = wv;
    }
    // ---- gate weights (r cols J, u cols 1024+J) -> pinned VGPRs ----
    s8v bgf[2][8];
    #pragma unroll
    for (int kk = 0; kk < 8; ++kk) {
        bgf[0][kk] = ld_b128_pin(WgT + (size_t)(J + l15) * 2048 + 1024 + kb + kk * 32 + kg * 8);
        bgf[1][kk] = ld_b128_pin(WgT + (size_t)(1024 + J + l15) * 2048 + 1024 + kb + kk * 32 + kg * 8);
    }
    vm_drain_schedfence();

    // epilogue mapping: 2 adjacent cols x 1 batch per thread (32 b x 16 c)
    const int b  = tid >> 3;                  // 0..31
    const int c0 = (tid & 7) * 2;             // 0,2,..,14
    const float2 bgr = { bg[J + c0],        bg[J + c0 + 1] };
    const float2 bgu = { bg[1024 + J + c0], bg[1024 + J + c0 + 1] };
    const float2 bcp = { bc[J + c0],        bc[J + c0 + 1] };

    __syncthreads();                          // wc_l ready

    // R5-proven barrier: relaxed counter, fence-free
    auto gbar = [&](unsigned tgt) {
        asm volatile("s_waitcnt vmcnt(0)" ::: "memory");   // sc1 data at LLC first
        __syncthreads();
        if (tid == 0) {
            __hip_atomic_fetch_add(bar, 1u, __ATOMIC_RELAXED, __HIP_MEMORY_SCOPE_AGENT);
            while (__hip_atomic_load(bar, __ATOMIC_RELAXED, __HIP_MEMORY_SCOPE_AGENT) < tgt)
                __builtin_amdgcn_s_sleep(1);
        }
        __syncthreads();
    };

    float h0 = 0.f, h1 = 0.f;                 // own h (register-resident)
    float u0 = 0.f, u1 = 0.f;

    for (int t = 0; t < TT; ++t) {
        const size_t bt = (size_t)b * TT + t;
        // ================= phase G: r_J, u_J =================
        ushort4 xgp = *(const ushort4*)(Xg2 + bt * 2048 + (size_t)(J + c0) * 2);
        unsigned xcp = *(const unsigned*)(Xcb + bt * 1024 + J + c0);

        s8v a[2][8];
        #pragma unroll
        for (int m = 0; m < 2; ++m)
            #pragma unroll
            for (int kk = 0; kk < 8; ++kk)
                a[m][kk] = ld_b128_sc(hb + (size_t)(m * 16 + l15) * 1024 + kb + kk * 32 + kg * 8);
        vm_drain_schedfence();

        f4v acc[2][2];
        #pragma unroll
        for (int m = 0; m < 2; ++m)
            #pragma unroll
            for (int n = 0; n < 2; ++n) acc[m][n] = (f4v){0.f, 0.f, 0.f, 0.f};
        #pragma unroll
        for (int kk = 0; kk < 8; ++kk)
            #pragma unroll
            for (int m = 0; m < 2; ++m)
                #pragma unroll
                for (int n = 0; n < 2; ++n)
                    acc[m][n] = __builtin_amdgcn_mfma_f32_16x16x32_bf16(a[m][kk], bgf[n][kk], acc[m][n], 0, 0, 0);

        #pragma unroll
        for (int m = 0; m < 2; ++m)
            #pragma unroll
            for (int n = 0; n < 2; ++n)
                #pragma unroll
                for (int i = 0; i < 4; ++i)
                    redg[wave][m * 16 + kg * 4 + i][n * 16 + l15] = acc[m][n][i];
        __syncthreads();

        {
            float2 pr = {0.f, 0.f}, pu = {0.f, 0.f};
            #pragma unroll
            for (int wv = 0; wv < 4; ++wv) {
                float2 p = *(const float2*)&redg[wv][b][c0];
                float2 q = *(const float2*)&redg[wv][b][16 + c0];
                pr.x += p.x; pr.y += p.y;
                pu.x += q.x; pu.y += q.y;
            }
            pr.x += bf2f(xgp.x) + bgr.x;  pu.x += bf2f(xgp.y) + bgu.x;
            pr.y += bf2f(xgp.z) + bgr.y;  pu.y += bf2f(xgp.w) + bgu.y;
            float r0 = 1.f / (1.f + __expf(-pr.x));
            float r1 = 1.f / (1.f + __expf(-pr.y));
            u0 = 1.f / (1.f + __expf(-pu.x));
            u1 = 1.f / (1.f + __expf(-pu.y));
            unsigned pk = (unsigned)f2bf(r0 * h0) | ((unsigned)f2bf(r1 * h1) << 16);
            st_b32_sc(rhb + (size_t)b * 1024 + J + c0, pk);
        }
        gbar((unsigned)(2 * t + 1) * NBLK);

        // ================= phase C: cand_J + update =================
        s8v ac[2][8];
        #pragma unroll
        for (int m = 0; m < 2; ++m)
            #pragma unroll
            for (int kk = 0; kk < 8; ++kk)
                ac[m][kk] = ld_b128_sc(rhb + (size_t)(m * 16 + l15) * 1024 + kb + kk * 32 + kg * 8);
        vm_drain_schedfence();

        f4v acc2[2];
        acc2[0] = (f4v){0.f, 0.f, 0.f, 0.f};
        acc2[1] = (f4v){0.f, 0.f, 0.f, 0.f};
        #pragma unroll
        for (int kk = 0; kk < 8; ++kk) {
            int k = kb + kk * 32 + kg * 8;
            s8v bcf = *(const s8v*)&wc_l[l15 * 1024 + (k ^ ((l15 & 7) << 3))];
            #pragma unroll
            for (int m = 0; m < 2; ++m)
                acc2[m] = __builtin_amdgcn_mfma_f32_16x16x32_bf16(ac[m][kk], bcf, acc2[m], 0, 0, 0);
        }
        float* redc = (float*)redg;           // [4][32][16]
        #pragma unroll
        for (int m = 0; m < 2; ++m)
            #pragma unroll
            for (int i = 0; i < 4; ++i)
                redc[((size_t)wave * 32 + m * 16 + kg * 4 + i) * 16 + l15] = acc2[m][i];
        __syncthreads();

        {
            float2 pc = {0.f, 0.f};
            #pragma unroll
            for (int wv = 0; wv < 4; ++wv) {
                float2 p = *(const float2*)&redc[((size_t)wv * 32 + b) * 16 + c0];
                pc.x += p.x; pc.y += p.y;
            }
            float cv0 = pc.x + bf2f((unsigned short)(xcp & 0xffff)) + bcp.x;
            float cv1 = pc.y + bf2f((unsigned short)(xcp >> 16)) + bcp.y;
            cv0 = fminf(fmaxf(cv0, -15.f), 15.f);
            cv1 = fminf(fmaxf(cv1, -15.f), 15.f);
            float e0 = __expf(2.f * cv0), e1 = __expf(2.f * cv1);
            float t0 = (e0 - 1.f) / (e0 + 1.f);
            float t1 = (e1 - 1.f) / (e1 + 1.f);
            h0 = u0 * h0 + (1.f - u0) * t0;
            h1 = u1 * h1 + (1.f - u1) * t1;
            st_b32_sc(hb + (size_t)b * 1024 + J + c0,
                      (unsigned)f2bf(h0) | ((unsigned)f2bf(h1) << 16));
            *(float2*)(out + bt * 1024 + J + c0) = make_float2(h0, h1);
        }
        if (t + 1 < TT) gbar((unsigned)(2 * t + 2) * NBLK);
    }
}

// ===========================================================================
// Fallback per-step kernels (round-2, verified) — used only if ws too small.
// ===========================================================================
__global__ __launch_bounds__(256) void gru_gates2(
    const unsigned short* __restrict__ hb, const unsigned short* __restrict__ WgT,
    const unsigned short* __restrict__ Xgb, const float* __restrict__ bg,
    const float* __restrict__ h, unsigned short* __restrict__ rhb,
    float* __restrict__ ubuf, int t)
{
    __shared__ unsigned short hb_l[32][1032];
    __shared__ unsigned short Wl[16][1032];
    __shared__ float red[4][32][16];
    const int tid = threadIdx.x, lane = tid & 63, wave = tid >> 6;
    const int l15 = lane & 15, kg = lane >> 4;
    const int j0 = blockIdx.x * 16;
    #pragma unroll
    for (int it = 0; it < 16; ++it) {
        int c = tid + it * 256; int r = c >> 7, off = (c & 127) * 8;
        *(s8v*)&hb_l[r][off] = *(const s8v*)(hb + (size_t)r * 1024 + off);
    }
    #pragma unroll
    for (int it = 0; it < 8; ++it) {
        int c = tid + it * 256; int r = c >> 7, off = (c & 127) * 8;
        *(s8v*)&Wl[r][off] = *(const s8v*)(WgT + (size_t)(j0 + r) * 2048 + 1024 + off);
    }
    __syncthreads();
    f4v acc0 = (f4v){0.f,0.f,0.f,0.f}, acc1 = (f4v){0.f,0.f,0.f,0.f};
    const int kbase = wave * 256;
    #pragma unroll
    for (int kk = 0; kk < 8; ++kk) {
        int k = kbase + kk * 32 + kg * 8;
        s8v a0 = *(const s8v*)&hb_l[l15][k];
        s8v a1 = *(const s8v*)&hb_l[16 + l15][k];
        s8v bv = *(const s8v*)&Wl[l15][k];
        acc0 = __builtin_amdgcn_mfma_f32_16x16x32_bf16(a0, bv, acc0, 0, 0, 0);
        acc1 = __builtin_amdgcn_mfma_f32_16x16x32_bf16(a1, bv, acc1, 0, 0, 0);
    }
    #pragma unroll
    for (int i = 0; i < 4; ++i) {
        red[wave][kg * 4 + i][l15] = acc0[i];
        red[wave][16 + kg * 4 + i][l15] = acc1[i];
    }
    __syncthreads();
    for (int e = tid; e < 512; e += 256) {
        int b = e >> 4, col = e & 15;
        int j = j0 + col;
        float pre = red[0][b][col] + red[1][b][col] + red[2][b][col] + red[3][b][col];
        pre += bf2f(Xgb[((size_t)b * TT + t) * 2048 + j]) + bg[j];
        float s = 1.f / (1.f + __expf(-pre));
        if (j < UU) rhb[b * UU + j] = f2bf(s * h[b * UU + j]);
        else        ubuf[b * UU + (j - UU)] = s;
    }
}

__global__ __launch_bounds__(256) void gru_cand2(
    const unsigned short* __restrict__ rhb, const unsigned short* __restrict__ WcT,
    const unsigned short* __restrict__ Xcb, const float* __restrict__ bc,
    const float* __restrict__ ubuf, float* __restrict__ h,
    unsigned short* __restrict__ hb, float* __restrict__ out, int t)
{
    __shared__ unsigned short rh_l[32][1032];
    __shared__ unsigned short Wl[16][1032];
    __shared__ float red[4][32][16];
    const int tid = threadIdx.x, lane = tid & 63, wave = tid >> 6;
    const int l15 = lane & 15, kg = lane >> 4;
    const int j0 = blockIdx.x * 16;
    #pragma unroll
    for (int it = 0; it < 16; ++it) {
        int c = tid + it * 256; int r = c >> 7, off = (c & 127) * 8;
        *(s8v*)&rh_l[r][off] = *(const s8v*)(rhb + (size_t)r * 1024 + off);
    }
    #pragma unroll
    for (int it = 0; it < 8; ++it) {
        int c = tid + it * 256; int r = c >> 7, off = (c & 127) * 8;
        *(s8v*)&Wl[r][off] = *(const s8v*)(WcT + (size_t)(j0 + r) * 2048 + 1024 + off);
    }
    __syncthreads();
    f4v acc0 = (f4v){0.f,0.f,0.f,0.f}, acc1 = (f4v){0.f,0.f,0.f,0.f};
    const int kbase = wave * 256;
    #pragma unroll
    for (int kk = 0; kk < 8; ++kk) {
        int k = kbase + kk * 32 + kg * 8;
        s8v a0 = *(const s8v*)&rh_l[l15][k];
        s8v a1 = *(const s8v*)&rh_l[16 + l15][k];
        s8v bv = *(const s8v*)&Wl[l15][k];
        acc0 = __builtin_amdgcn_mfma_f32_16x16x32_bf16(a0, bv, acc0, 0, 0, 0);
        acc1 = __builtin_amdgcn_mfma_f32_16x16x32_bf16(a1, bv, acc1, 0, 0, 0);
    }
    #pragma unroll
    for (int i = 0; i < 4; ++i) {
        red[wave][kg * 4 + i][l15] = acc0[i];
        red[wave][16 + kg * 4 + i][l15] = acc1[i];
    }
    __syncthreads();
    for (int e = tid; e < 512; e += 256) {
        int b = e >> 4, col = e & 15;
        int j = j0 + col;
        float pre = red[0][b][col] + red[1][b][col] + red[2][b][col] + red[3][b][col];
        pre += bf2f(Xcb[((size_t)b * TT + t) * 1024 + j]) + bc[j];
        float cv = tanhf(pre);
        float u  = ubuf[b * UU + j];
        float hvv = h[b * UU + j];
        float hn = u * hvv + (1.f - u) * cv;
        h[b * UU + j]  = hn;
        hb[b * UU + j] = f2bf(hn);
        out[((size_t)b * TT + t) * UU + j] = hn;
    }
}

// ===========================================================================
extern "C" void kernel_launch(void* const* d_in, const int* in_sizes, int n_in,
                              void* d_out, int out_size, void* d_ws, size_t ws_size,
                              hipStream_t stream) {
    const float* x  = (const float*)d_in[0];
    const float* Wg = (const float*)d_in[1];
    const float* bg = (const float*)d_in[2];
    const float* Wc = (const float*)d_in[3];
    const float* bc = (const float*)d_in[4];
    float* out = (float*)d_out;

    const size_t XB_B  = (size_t)BB * TT * FF * 2;
    const size_t WGT_B = (size_t)2 * UU * (FF + UU) * 2;
    const size_t WCT_B = (size_t)UU * (FF + UU) * 2;
    const size_t XG_B  = (size_t)BB * TT * 2 * UU * 2;
    const size_t XC_B  = (size_t)BB * TT * UU * 2;
    const size_t H_B   = (size_t)BB * UU * 4;
    const size_t HB_B  = (size_t)BB * UU * 2;
    const size_t BAR_B = 4096;
    const size_t NEED  = XB_B + WGT_B + WCT_B + XG_B + XC_B + H_B + HB_B * 2 + H_B + BAR_B;

    char* p = (char*)d_ws;
    unsigned short* xb  = (unsigned short*)p;            p += XB_B;
    unsigned short* WgT = (unsigned short*)p;            p += WGT_B;
    unsigned short* WcT = (unsigned short*)p;            p += WCT_B;
    unsigned short* Xgb = (unsigned short*)p;            p += XG_B;   // interleaved for persistent
    unsigned short* Xcb = (unsigned short*)p;            p += XC_B;
    float*          h   = (float*)p;                     p += H_B;   // fallback only
    unsigned short* hb  = (unsigned short*)p;            p += HB_B;
    unsigned short* rhb = (unsigned short*)p;            p += HB_B;
    float*          ub  = (float*)p;                     p += H_B;   // fallback only
    unsigned*       bar = (unsigned*)p;                  p += BAR_B;

    const bool persistent = (ws_size >= NEED);

    // ---- one-time prep ----
    cvt_bf16<<<(BB * TT * FF / 4 + 255) / 256, 256, 0, stream>>>(x, xb, BB * TT * FF / 4);
    transpose_bf16<FF + UU, 2 * UU><<<dim3(64, 64), dim3(32, 8), 0, stream>>>(Wg, WgT);
    transpose_bf16<FF + UU, UU>    <<<dim3(32, 64), dim3(32, 8), 0, stream>>>(Wc, WcT);
    if (persistent)
        gemm_xproj<true><<<dim3(2 * UU / 128, BB * TT / 128), 256, 0, stream>>>(xb, WgT, Xgb, 2 * UU);
    else
        gemm_xproj<false><<<dim3(2 * UU / 128, BB * TT / 128), 256, 0, stream>>>(xb, WgT, Xgb, 2 * UU);
    gemm_xproj<false><<<dim3(UU / 128, BB * TT / 128), 256, 0, stream>>>(xb, WcT, Xcb, UU);
    hipMemsetAsync(h,   0, H_B,   stream);
    hipMemsetAsync(hb,  0, HB_B,  stream);
    hipMemsetAsync(bar, 0, BAR_B, stream);

    if (persistent) {
        gru_fast<<<NBLK, 256, 0, stream>>>(WgT, WcT, Xgb, Xcb, bg, bc,
                                           hb, rhb, out, bar);
    } else {
        for (int t = 0; t < TT; ++t) {
            gru_gates2<<<128, 256, 0, stream>>>(hb, WgT, Xgb, bg, h, rhb, ub, t);
            gru_cand2 <<< 64, 256, 0, stream>>>(rhb, WcT, Xcb, bc, ub, h, hb, out, t);
        }
    }
}